// Round 1
// baseline (1169.780 us; speedup 1.0000x reference)
//
#include <hip/hip_runtime.h>
#include <hip/hip_bf16.h>
#include <cstdint>
#include <cstddef>

#define TPB 256
#define SCAN_CHUNK 1024

__device__ __forceinline__ float sigmoidf_(float x) {
    return 1.0f / (1.0f + __expf(-x));
}

// ---------------------------------------------------------------- graph prep

__global__ __launch_bounds__(TPB) void k_init(float* deg, int* counts, int n) {
    int i = blockIdx.x * TPB + threadIdx.x;
    if (i < n) { deg[i] = 1.0f; counts[i] = 0; }   // deg starts at 1.0 (self-loop weight)
}

__global__ __launch_bounds__(TPB) void k_edge_pass1(const int* __restrict__ dst,
                                                    const float* __restrict__ ew,
                                                    float* __restrict__ deg,
                                                    int* __restrict__ counts, int E) {
    int e = blockIdx.x * TPB + threadIdx.x;
    if (e < E) {
        int d = dst[e];
        atomicAdd(&deg[d], ew[e]);
        atomicAdd(&counts[d], 1);
    }
}

__global__ __launch_bounds__(TPB) void k_dinv(const float* __restrict__ deg,
                                              float* __restrict__ dinv, int n) {
    int i = blockIdx.x * TPB + threadIdx.x;
    if (i < n) {
        float d = deg[i];
        dinv[i] = (d > 0.0f) ? rsqrtf(d) : 0.0f;
    }
}

// exclusive scan of counts[0..n) into rowptr, 1024-elem chunks
__global__ __launch_bounds__(TPB) void k_scan_a(const int* __restrict__ counts,
                                                int* __restrict__ rowptr,
                                                int* __restrict__ bsums, int n) {
    __shared__ int s[SCAN_CHUNK];
    int base = blockIdx.x * SCAN_CHUNK;
    int orig[4];
    #pragma unroll
    for (int j0 = 0; j0 < 4; ++j0) {
        int j = threadIdx.x + j0 * TPB;
        int v = (base + j < n) ? counts[base + j] : 0;
        orig[j0] = v;
        s[j] = v;
    }
    __syncthreads();
    for (int off = 1; off < SCAN_CHUNK; off <<= 1) {
        int t[4];
        #pragma unroll
        for (int j0 = 0; j0 < 4; ++j0) {
            int j = threadIdx.x + j0 * TPB;
            t[j0] = (j >= off) ? s[j - off] : 0;
        }
        __syncthreads();
        #pragma unroll
        for (int j0 = 0; j0 < 4; ++j0) {
            int j = threadIdx.x + j0 * TPB;
            s[j] += t[j0];
        }
        __syncthreads();
    }
    #pragma unroll
    for (int j0 = 0; j0 < 4; ++j0) {
        int j = threadIdx.x + j0 * TPB;
        if (base + j < n) rowptr[base + j] = s[j] - orig[j0];   // exclusive
    }
    if (threadIdx.x == 0) bsums[blockIdx.x] = s[SCAN_CHUNK - 1];
}

__global__ void k_scan_b(int* bsums, int nb) {
    if (threadIdx.x == 0 && blockIdx.x == 0) {
        int acc = 0;
        for (int i = 0; i < nb; ++i) { int v = bsums[i]; bsums[i] = acc; acc += v; }
    }
}

__global__ __launch_bounds__(TPB) void k_scan_c(int* __restrict__ rowptr,
                                                const int* __restrict__ bsums,
                                                int* __restrict__ counts, int n, int E) {
    int i = blockIdx.x * TPB + threadIdx.x;
    if (i < n) {
        rowptr[i] += bsums[i / SCAN_CHUNK];
        counts[i] = 0;                       // reset for fill pass
    }
    if (i == 0) rowptr[n] = E;
}

__global__ __launch_bounds__(TPB) void k_fill(const int* __restrict__ src,
                                              const int* __restrict__ dst,
                                              const float* __restrict__ ew,
                                              const float* __restrict__ dinv,
                                              const int* __restrict__ rowptr,
                                              int* __restrict__ counts,
                                              int* __restrict__ colIdx,
                                              float* __restrict__ valNorm, int E) {
    int e = blockIdx.x * TPB + threadIdx.x;
    if (e < E) {
        int d = dst[e];
        int s = src[e];
        int pos = atomicAdd(&counts[d], 1);
        int slot = rowptr[d] + pos;
        colIdx[slot] = s;
        valNorm[slot] = dinv[s] * ew[e] * dinv[d];
    }
}

// ---------------------------------------------------------------- aggregation
// one wave (64 lanes) per node; D=128 -> float2/lane, D=64 -> float/lane
// ACT: 1 = tanh, 2 = sigmoid
template<int D, int ACT>
__global__ __launch_bounds__(TPB) void k_agg(const float* __restrict__ h,
                                             const int* __restrict__ rowptr,
                                             const int* __restrict__ colIdx,
                                             const float* __restrict__ valNorm,
                                             const float* __restrict__ dinv,
                                             const float* __restrict__ bias,
                                             float* __restrict__ out, int ldo, int n) {
    const int lane = threadIdx.x & 63;
    const int node = blockIdx.x * 4 + (threadIdx.x >> 6);
    if (node >= n) return;
    constexpr int PER = D / 64;
    float acc[PER];
    const float di = dinv[node];
    const float sw = di * di;                // self-loop norm = dinv*1*dinv
    if constexpr (PER == 2) {
        const float2 hv = *(const float2*)&h[(size_t)node * D + lane * 2];
        acc[0] = hv.x * sw;
        acc[1] = hv.y * sw;
    } else {
        acc[0] = h[(size_t)node * D + lane] * sw;
    }
    const int beg = rowptr[node];
    const int end = rowptr[node + 1];
    for (int e = beg; e < end; ++e) {
        const int s = colIdx[e];
        const float nv = valNorm[e];
        if constexpr (PER == 2) {
            const float2 hv = *(const float2*)&h[(size_t)s * D + lane * 2];
            acc[0] += hv.x * nv;
            acc[1] += hv.y * nv;
        } else {
            acc[0] += h[(size_t)s * D + lane] * nv;
        }
    }
    #pragma unroll
    for (int j = 0; j < PER; ++j) {
        const int c = (PER == 2) ? (lane * 2 + j) : lane;
        float v = acc[j] + bias[c];
        if constexpr (ACT == 1) v = tanhf(v);
        else                    v = sigmoidf_(v);
        out[(size_t)node * ldo + c] = v;
    }
}

// ---------------------------------------------------------------- dense GEMM
// C[r, coff + c] = act(A[r,:] @ W[:,c] + bias[c]); W is K x M row-major.
// A tile staged in LDS (broadcast reads). W staged in LDS only when small
// enough; otherwise streamed from global (L2-resident, coalesced).
// CI: cols per thread (adjacent pair when 2). RI: rows per thread.
// ACT: 0 none, 1 tanh, 2 sigmoid.
template<int K, int M, int CI, int RI, int ACT>
__global__ __launch_bounds__(TPB) void k_gemm(const float* __restrict__ A, int lda,
                                              const float* __restrict__ W,
                                              const float* __restrict__ bias,
                                              float* __restrict__ C, int ldc, int coff,
                                              int n) {
    constexpr int TPR = M / CI;              // threads covering one row's M cols
    constexpr int G   = TPB / TPR;           // row-groups per block
    constexpr int RT  = G * RI;              // rows per tile
    constexpr bool STAGE_W = ((K * M + RT * K) * 4) <= (48 * 1024);
    static_assert(TPB % TPR == 0, "bad geometry");
    static_assert(CI == 1 || CI == 2, "CI in {1,2}");

    __shared__ float Alds[RT * K];
    __shared__ float Wlds[STAGE_W ? (K * M) : 1];
    if constexpr (STAGE_W) {
        for (int i = threadIdx.x; i < K * M; i += TPB) Wlds[i] = W[i];
    }
    const int c0 = threadIdx.x % TPR;
    const int rg = threadIdx.x / TPR;

    for (int tile = blockIdx.x; tile * RT < n; tile += gridDim.x) {
        const int rbase = tile * RT;
        __syncthreads();
        for (int i = threadIdx.x; i < RT * K; i += TPB) {
            int rr = i / K;
            int r  = rbase + rr;
            Alds[i] = (r < n) ? A[(size_t)r * lda + (i - rr * K)] : 0.0f;
        }
        __syncthreads();

        float acc[RI][CI];
        #pragma unroll
        for (int j = 0; j < RI; ++j)
            #pragma unroll
            for (int t = 0; t < CI; ++t) acc[j][t] = 0.0f;

        const float* Ab = &Alds[rg * RI * K];
        #pragma unroll 4
        for (int k = 0; k < K; ++k) {
            float wv[CI];
            if constexpr (CI == 2) {
                float2 w2;
                if constexpr (STAGE_W) w2 = *(const float2*)&Wlds[k * M + c0 * 2];
                else                   w2 = *(const float2*)&W[k * M + c0 * 2];
                wv[0] = w2.x; wv[1] = w2.y;
            } else {
                wv[0] = STAGE_W ? Wlds[k * M + c0] : W[k * M + c0];
            }
            float av[RI];
            #pragma unroll
            for (int j = 0; j < RI; ++j) av[j] = Ab[j * K + k];
            #pragma unroll
            for (int j = 0; j < RI; ++j)
                #pragma unroll
                for (int t = 0; t < CI; ++t) acc[j][t] += av[j] * wv[t];
        }

        #pragma unroll
        for (int j = 0; j < RI; ++j) {
            const int r = rbase + rg * RI + j;
            if (r < n) {
                #pragma unroll
                for (int t = 0; t < CI; ++t) {
                    const int c = (CI == 2) ? (c0 * 2 + t) : c0;
                    float v = acc[j][t];
                    if (bias) v += bias[c];
                    if constexpr (ACT == 1) v = tanhf(v);
                    else if constexpr (ACT == 2) v = sigmoidf_(v);
                    C[(size_t)r * ldc + coff + c] = v;
                }
            }
        }
    }
}

// enc[:, 96:128] = sigmoid(pr * prW + prB)
__global__ __launch_bounds__(TPB) void k_pr(const float* __restrict__ pr,
                                            const float* __restrict__ prW,
                                            const float* __restrict__ prB,
                                            float* __restrict__ enc, int n) {
    int i = blockIdx.x * TPB + threadIdx.x;
    if (i < n * 32) {
        int node = i >> 5;
        int c = i & 31;
        float v = pr[node] * prW[c] + prB[c];
        enc[(size_t)node * 128 + 96 + c] = sigmoidf_(v);
    }
}

// ---------------------------------------------------------------- launch

extern "C" void kernel_launch(void* const* d_in, const int* in_sizes, int n_in,
                              void* d_out, int out_size, void* d_ws, size_t ws_size,
                              hipStream_t stream) {
    const float* feat = (const float*)d_in[0];
    const float* gdv  = (const float*)d_in[1];
    const float* pr   = (const float*)d_in[2];
    const int*   eidx = (const int*)d_in[3];
    const float* ew   = (const float*)d_in[4];
    const float* W1   = (const float*)d_in[5];
    const float* b1   = (const float*)d_in[6];
    const float* W2   = (const float*)d_in[7];
    const float* b2   = (const float*)d_in[8];
    const float* gdvW = (const float*)d_in[9];
    const float* gdvB = (const float*)d_in[10];
    const float* prW  = (const float*)d_in[11];
    const float* prB  = (const float*)d_in[12];
    const float* eW1  = (const float*)d_in[13];
    const float* eB1  = (const float*)d_in[14];
    const float* eW2  = (const float*)d_in[15];
    const float* eB2  = (const float*)d_in[16];
    float* out = (float*)d_out;

    const int N = in_sizes[0] / 128;
    const int E = in_sizes[4];
    const int* srcA = eidx;         // edge_index row 0
    const int* dstA = eidx + E;     // edge_index row 1

    // ---- workspace carve (256B aligned) ----
    char* p = (char*)d_ws;
    auto alloc = [&](size_t bytes) {
        char* r = p;
        p += (bytes + 255) & ~(size_t)255;
        return r;
    };
    float* deg     = (float*)alloc((size_t)N * 4);
    float* dinv    = (float*)alloc((size_t)N * 4);
    int*   rowptr  = (int*)  alloc((size_t)(N + 1) * 4);
    int*   counts  = (int*)  alloc((size_t)N * 4);
    int*   bsums   = (int*)  alloc(256 * 4);
    int*   colIdx  = (int*)  alloc((size_t)E * 4);
    float* valNorm = (float*)alloc((size_t)E * 4);
    float* bufA    = (float*)alloc((size_t)N * 128 * 4);   // h -> h2 -> enc1
    float* bufB    = (float*)alloc((size_t)N * 128 * 4);   // h1 -> enc

    const int nbN = (N + TPB - 1) / TPB;
    const int nbE = (E + TPB - 1) / TPB;
    const int nscan = (N + SCAN_CHUNK - 1) / SCAN_CHUNK;

    // CSR build + normalization
    k_init<<<nbN, TPB, 0, stream>>>(deg, counts, N);
    k_edge_pass1<<<nbE, TPB, 0, stream>>>(dstA, ew, deg, counts, E);
    k_dinv<<<nbN, TPB, 0, stream>>>(deg, dinv, N);
    k_scan_a<<<nscan, TPB, 0, stream>>>(counts, rowptr, bsums, N);
    k_scan_b<<<1, 64, 0, stream>>>(bsums, nscan);
    k_scan_c<<<nbN, TPB, 0, stream>>>(rowptr, bsums, counts, N, E);
    k_fill<<<nbE, TPB, 0, stream>>>(srcA, dstA, ew, dinv, rowptr, counts, colIdx, valNorm, E);

    // h = feat @ W1                      (bufA, ld 128)   RT=16
    k_gemm<128, 128, 2, 4, 0><<<(N + 15) / 16, TPB, 0, stream>>>(
        feat, 128, W1, nullptr, bufA, 128, 0, N);
    // h1 = tanh(agg(h) + b1)             (bufB, ld 128)
    k_agg<128, 1><<<(N + 3) / 4, TPB, 0, stream>>>(
        bufA, rowptr, colIdx, valNorm, dinv, b1, bufB, 128, N);
    // h2 = h1 @ W2                       (bufA, ld 64)    RT=16
    k_gemm<128, 64, 1, 4, 0><<<(N + 15) / 16, TPB, 0, stream>>>(
        bufB, 128, W2, nullptr, bufA, 64, 0, N);
    // enc[:,0:64] = sigmoid(agg(h2)+b2)  (bufB, ld 128)
    k_agg<64, 2><<<(N + 3) / 4, TPB, 0, stream>>>(
        bufA, rowptr, colIdx, valNorm, dinv, b2, bufB, 128, N);
    // enc[:,64:96] = sigmoid(gdv @ gdvW + gdvB)           RT=32
    k_gemm<73, 32, 1, 4, 2><<<(N + 31) / 32, TPB, 0, stream>>>(
        gdv, 73, gdvW, gdvB, bufB, 128, 64, N);
    // enc[:,96:128] = sigmoid(pr * prW + prB)
    k_pr<<<((size_t)N * 32 + TPB - 1) / TPB, TPB, 0, stream>>>(pr, prW, prB, bufB, N);
    // enc1 = tanh(enc @ eW1 + eB1)       (bufA, ld 128)   RT=16
    k_gemm<128, 128, 2, 4, 1><<<(N + 15) / 16, TPB, 0, stream>>>(
        bufB, 128, eW1, eB1, bufA, 128, 0, N);
    // out = enc1 @ eW2 + eB2             (d_out)          RT=16
    k_gemm<128, 128, 2, 4, 0><<<(N + 15) / 16, TPB, 0, stream>>>(
        bufA, 128, eW2, eB2, out, 128, 0, N);
}

// Round 3
// 915.855 us; speedup vs baseline: 1.2773x; 1.2773x over previous
//
#include <hip/hip_runtime.h>
#include <hip/hip_bf16.h>
#include <cstdint>
#include <cstddef>

#define TPB 256
#define SCAN_CHUNK 1024

typedef short bf16x8 __attribute__((ext_vector_type(8)));
typedef float f32x4 __attribute__((ext_vector_type(4)));

__device__ __forceinline__ float sigmoidf_(float x) {
    return 1.0f / (1.0f + __expf(-x));
}
__device__ __forceinline__ unsigned short f2bf(float x) {   // RNE
    unsigned u = __float_as_uint(x);
    u += 0x7FFF + ((u >> 16) & 1);
    return (unsigned short)(u >> 16);
}
__device__ __forceinline__ float bf2f(unsigned short b) {
    return __uint_as_float(((unsigned)b) << 16);
}

// ---------------------------------------------------------------- graph prep

__global__ __launch_bounds__(TPB) void k_init(float* deg, int* counts, int n) {
    int i = blockIdx.x * TPB + threadIdx.x;
    if (i < n) { deg[i] = 1.0f; counts[i] = 0; }   // self-loop weight 1.0
}

__global__ __launch_bounds__(TPB) void k_edge_pass1(const int* __restrict__ dst,
                                                    const float* __restrict__ ew,
                                                    float* __restrict__ deg,
                                                    int* __restrict__ counts, int E) {
    int e = blockIdx.x * TPB + threadIdx.x;
    if (e < E) {
        int d = dst[e];
        atomicAdd(&deg[d], ew[e]);
        atomicAdd(&counts[d], 1);
    }
}

__global__ __launch_bounds__(TPB) void k_dinv(const float* __restrict__ deg,
                                              float* __restrict__ dinv, int n) {
    int i = blockIdx.x * TPB + threadIdx.x;
    if (i < n) {
        float d = deg[i];
        dinv[i] = (d > 0.0f) ? rsqrtf(d) : 0.0f;
    }
}

__global__ __launch_bounds__(TPB) void k_scan_a(const int* __restrict__ counts,
                                                int* __restrict__ rowptr,
                                                int* __restrict__ bsums, int n) {
    __shared__ int s[SCAN_CHUNK];
    int base = blockIdx.x * SCAN_CHUNK;
    int orig[4];
    #pragma unroll
    for (int j0 = 0; j0 < 4; ++j0) {
        int j = threadIdx.x + j0 * TPB;
        int v = (base + j < n) ? counts[base + j] : 0;
        orig[j0] = v;
        s[j] = v;
    }
    __syncthreads();
    for (int off = 1; off < SCAN_CHUNK; off <<= 1) {
        int t[4];
        #pragma unroll
        for (int j0 = 0; j0 < 4; ++j0) {
            int j = threadIdx.x + j0 * TPB;
            t[j0] = (j >= off) ? s[j - off] : 0;
        }
        __syncthreads();
        #pragma unroll
        for (int j0 = 0; j0 < 4; ++j0) {
            int j = threadIdx.x + j0 * TPB;
            s[j] += t[j0];
        }
        __syncthreads();
    }
    #pragma unroll
    for (int j0 = 0; j0 < 4; ++j0) {
        int j = threadIdx.x + j0 * TPB;
        if (base + j < n) rowptr[base + j] = s[j] - orig[j0];
    }
    if (threadIdx.x == 0) bsums[blockIdx.x] = s[SCAN_CHUNK - 1];
}

__global__ void k_scan_b(int* bsums, int nb) {
    if (threadIdx.x == 0 && blockIdx.x == 0) {
        int acc = 0;
        for (int i = 0; i < nb; ++i) { int v = bsums[i]; bsums[i] = acc; acc += v; }
    }
}

__global__ __launch_bounds__(TPB) void k_scan_c(int* __restrict__ rowptr,
                                                const int* __restrict__ bsums,
                                                int* __restrict__ counts, int n, int E) {
    int i = blockIdx.x * TPB + threadIdx.x;
    if (i < n) {
        rowptr[i] += bsums[i / SCAN_CHUNK];
        counts[i] = 0;
    }
    if (i == 0) rowptr[n] = E;
}

__global__ __launch_bounds__(TPB) void k_fill(const int* __restrict__ src,
                                              const int* __restrict__ dst,
                                              const float* __restrict__ ew,
                                              const float* __restrict__ dinv,
                                              const int* __restrict__ rowptr,
                                              int* __restrict__ counts,
                                              int* __restrict__ colIdx,
                                              float* __restrict__ valNorm, int E) {
    int e = blockIdx.x * TPB + threadIdx.x;
    if (e < E) {
        int d = dst[e];
        int s = src[e];
        int pos = atomicAdd(&counts[d], 1);
        int slot = rowptr[d] + pos;
        colIdx[slot] = s;
        valNorm[slot] = dinv[s] * ew[e] * dinv[d];
    }
}

// ---------------------------------------------------------------- aggregation
// one wave per node, h in bf16; acc f32. ACT: 1 tanh, 2 sigmoid.
template<int D, int ACT>
__global__ __launch_bounds__(TPB) void k_agg(const unsigned short* __restrict__ h,
                                             const int* __restrict__ rowptr,
                                             const int* __restrict__ colIdx,
                                             const float* __restrict__ valNorm,
                                             const float* __restrict__ dinv,
                                             const float* __restrict__ bias,
                                             unsigned short* __restrict__ out,
                                             int ldo, int n) {
    const int lane = threadIdx.x & 63;
    const int node = blockIdx.x * 4 + (threadIdx.x >> 6);
    if (node >= n) return;
    constexpr int PER = D / 64;
    float acc[PER];
    const float di = dinv[node];
    const float sw = di * di;
    if constexpr (PER == 2) {
        unsigned hv = *(const unsigned*)&h[(size_t)node * D + lane * 2];
        acc[0] = bf2f((unsigned short)hv) * sw;
        acc[1] = bf2f((unsigned short)(hv >> 16)) * sw;
    } else {
        acc[0] = bf2f(h[(size_t)node * D + lane]) * sw;
    }
    const int beg = rowptr[node];
    const int end = rowptr[node + 1];
    for (int e = beg; e < end; ++e) {
        const int s = colIdx[e];         // wave-uniform -> scalar loads
        const float nv = valNorm[e];
        if constexpr (PER == 2) {
            unsigned hv = *(const unsigned*)&h[(size_t)s * D + lane * 2];
            acc[0] += bf2f((unsigned short)hv) * nv;
            acc[1] += bf2f((unsigned short)(hv >> 16)) * nv;
        } else {
            acc[0] += bf2f(h[(size_t)s * D + lane]) * nv;
        }
    }
    if constexpr (PER == 2) {
        float v0 = acc[0] + bias[lane * 2];
        float v1 = acc[1] + bias[lane * 2 + 1];
        if constexpr (ACT == 1) { v0 = tanhf(v0); v1 = tanhf(v1); }
        else                    { v0 = sigmoidf_(v0); v1 = sigmoidf_(v1); }
        unsigned pk = (unsigned)f2bf(v0) | ((unsigned)f2bf(v1) << 16);
        *(unsigned*)&out[(size_t)node * ldo + lane * 2] = pk;
    } else {
        float v = acc[0] + bias[lane];
        v = (ACT == 1) ? tanhf(v) : sigmoidf_(v);
        out[(size_t)node * ldo + lane] = f2bf(v);
    }
}

// ---------------------------------------------------------------- MFMA GEMM
// C(n x M) = act(A(n x 128) @ W(128 x M) + bias). K=128 in one LDS pass.
// BM=128 rows/block, 4 waves x 32 rows. XOR-swizzled LDS (256B rows).
// ACT: 0 none, 1 tanh, 2 sigmoid.
template<int M, int ACT, bool A_BF16, bool OUT_F32>
__global__ __launch_bounds__(TPB) void k_mgemm(const void* __restrict__ Ap,
                                               const float* __restrict__ W,
                                               const float* __restrict__ bias,
                                               void* __restrict__ Cp, int ldc,
                                               int coff, int n) {
    constexpr int K = 128;
    __shared__ __align__(16) unsigned short Al[128 * K];   // [row][k] swizzled
    __shared__ __align__(16) unsigned short Wt[M * K];     // [col][k] swizzled

    const int tid = threadIdx.x;
    const int rbase = blockIdx.x * 128;

    // stage W^T (f32 -> bf16), rows of Wt are output-cols
    for (int idx = tid; idx < K * M; idx += TPB) {
        int k = idx / M, m = idx % M;
        unsigned byte = (unsigned)(m * 256 + k * 2) ^ (unsigned)((m & 7) << 4);
        *(unsigned short*)((char*)Wt + byte) = f2bf(W[idx]);
    }
    // stage A tile, 8-elem (16B) chunks
    for (int ch = tid; ch < 128 * 16; ch += TPB) {
        int row = ch >> 4;
        int col8 = (ch & 15) * 8;
        int r = rbase + row;
        unsigned o4[4];
        if (r < n) {
            if constexpr (A_BF16) {
                uint4 v = *(const uint4*)((const unsigned short*)Ap + (size_t)r * 128 + col8);
                o4[0] = v.x; o4[1] = v.y; o4[2] = v.z; o4[3] = v.w;
            } else {
                float4 a = *(const float4*)((const float*)Ap + (size_t)r * 128 + col8);
                float4 b = *(const float4*)((const float*)Ap + (size_t)r * 128 + col8 + 4);
                o4[0] = (unsigned)f2bf(a.x) | ((unsigned)f2bf(a.y) << 16);
                o4[1] = (unsigned)f2bf(a.z) | ((unsigned)f2bf(a.w) << 16);
                o4[2] = (unsigned)f2bf(b.x) | ((unsigned)f2bf(b.y) << 16);
                o4[3] = (unsigned)f2bf(b.z) | ((unsigned)f2bf(b.w) << 16);
            }
        } else {
            o4[0] = o4[1] = o4[2] = o4[3] = 0u;
        }
        unsigned byte = (unsigned)(row * 256 + col8 * 2) ^ (unsigned)((row & 7) << 4);
        *(uint4*)((char*)Al + byte) = *(uint4*)o4;
    }
    __syncthreads();

    const int wave = tid >> 6;
    const int lane = tid & 63;
    const int lr = lane & 15;    // A-row / B-col / D-col within fragment
    const int lg = lane >> 4;    // k-group

    constexpr int MF = M / 16;
    f32x4 acc[2][MF];
    #pragma unroll
    for (int i = 0; i < 2; ++i)
        #pragma unroll
        for (int j = 0; j < MF; ++j) acc[i][j] = (f32x4){0.f, 0.f, 0.f, 0.f};

    #pragma unroll
    for (int kk = 0; kk < 4; ++kk) {
        const int kb = kk * 64 + lg * 16;       // byte offset within 256B row
        bf16x8 af[2];
        #pragma unroll
        for (int rf = 0; rf < 2; ++rf) {
            int row = wave * 32 + rf * 16 + lr;
            unsigned byte = (unsigned)(row * 256 + kb) ^ (unsigned)((row & 7) << 4);
            af[rf] = *(bf16x8*)((char*)Al + byte);
        }
        #pragma unroll
        for (int mf = 0; mf < MF; ++mf) {
            int col = mf * 16 + lr;
            unsigned byte = (unsigned)(col * 256 + kb) ^ (unsigned)((col & 7) << 4);
            bf16x8 bfg = *(bf16x8*)((char*)Wt + byte);
            acc[0][mf] = __builtin_amdgcn_mfma_f32_16x16x32_bf16(af[0], bfg, acc[0][mf], 0, 0, 0);
            acc[1][mf] = __builtin_amdgcn_mfma_f32_16x16x32_bf16(af[1], bfg, acc[1][mf], 0, 0, 0);
        }
    }

    // epilogue: D lane map col=lane&15, row=(lane>>4)*4+j  [m89-verified]
    #pragma unroll
    for (int rf = 0; rf < 2; ++rf) {
        #pragma unroll
        for (int j = 0; j < 4; ++j) {
            int row = rbase + wave * 32 + rf * 16 + lg * 4 + j;
            if (row < n) {
                #pragma unroll
                for (int mf = 0; mf < MF; ++mf) {
                    int col = mf * 16 + lr;
                    float v = acc[rf][mf][j] + (bias ? bias[col] : 0.0f);
                    if constexpr (ACT == 1) v = tanhf(v);
                    else if constexpr (ACT == 2) v = sigmoidf_(v);
                    if constexpr (OUT_F32)
                        ((float*)Cp)[(size_t)row * ldc + coff + col] = v;
                    else
                        ((unsigned short*)Cp)[(size_t)row * ldc + coff + col] = f2bf(v);
                }
            }
        }
    }
}

// ---------------------------------------------------------------- small SIMT GEMM (gdv)
// C[r, coff+c] = sigmoid(A[r,:]@W[:,c] + bias[c]), out bf16
template<int K, int M, int RI>
__global__ __launch_bounds__(TPB) void k_gemm_s(const float* __restrict__ A, int lda,
                                                const float* __restrict__ W,
                                                const float* __restrict__ bias,
                                                unsigned short* __restrict__ C, int ldc,
                                                int coff, int n) {
    constexpr int TPR = M;
    constexpr int G = TPB / TPR;
    constexpr int RT = G * RI;
    __shared__ float Alds[RT * K];
    __shared__ float Wlds[K * M];
    for (int i = threadIdx.x; i < K * M; i += TPB) Wlds[i] = W[i];

    const int c0 = threadIdx.x % TPR;
    const int rg = threadIdx.x / TPR;
    const int rbase = blockIdx.x * RT;

    for (int i = threadIdx.x; i < RT * K; i += TPB) {
        int rr = i / K;
        int r = rbase + rr;
        Alds[i] = (r < n) ? A[(size_t)r * lda + (i - rr * K)] : 0.0f;
    }
    __syncthreads();

    float acc[RI];
    #pragma unroll
    for (int j = 0; j < RI; ++j) acc[j] = 0.0f;
    const float* Ab = &Alds[rg * RI * K];
    #pragma unroll 4
    for (int k = 0; k < K; ++k) {
        float wv = Wlds[k * M + c0];
        #pragma unroll
        for (int j = 0; j < RI; ++j) acc[j] += Ab[j * K + k] * wv;
    }
    #pragma unroll
    for (int j = 0; j < RI; ++j) {
        int r = rbase + rg * RI + j;
        if (r < n) C[(size_t)r * ldc + coff + c0] = f2bf(sigmoidf_(acc[j] + bias[c0]));
    }
}

__global__ __launch_bounds__(TPB) void k_pr(const float* __restrict__ pr,
                                            const float* __restrict__ prW,
                                            const float* __restrict__ prB,
                                            unsigned short* __restrict__ enc, int n) {
    int i = blockIdx.x * TPB + threadIdx.x;
    if (i < n * 32) {
        int node = i >> 5;
        int c = i & 31;
        float v = pr[node] * prW[c] + prB[c];
        enc[(size_t)node * 128 + 96 + c] = f2bf(sigmoidf_(v));
    }
}

// ---------------------------------------------------------------- launch

extern "C" void kernel_launch(void* const* d_in, const int* in_sizes, int n_in,
                              void* d_out, int out_size, void* d_ws, size_t ws_size,
                              hipStream_t stream) {
    const float* feat = (const float*)d_in[0];
    const float* gdv  = (const float*)d_in[1];
    const float* pr   = (const float*)d_in[2];
    const int*   eidx = (const int*)d_in[3];
    const float* ew   = (const float*)d_in[4];
    const float* W1   = (const float*)d_in[5];
    const float* b1   = (const float*)d_in[6];
    const float* W2   = (const float*)d_in[7];
    const float* b2   = (const float*)d_in[8];
    const float* gdvW = (const float*)d_in[9];
    const float* gdvB = (const float*)d_in[10];
    const float* prW  = (const float*)d_in[11];
    const float* prB  = (const float*)d_in[12];
    const float* eW1  = (const float*)d_in[13];
    const float* eB1  = (const float*)d_in[14];
    const float* eW2  = (const float*)d_in[15];
    const float* eB2  = (const float*)d_in[16];
    float* out = (float*)d_out;

    const int N = in_sizes[0] / 128;
    const int E = in_sizes[4];
    const int* srcA = eidx;
    const int* dstA = eidx + E;

    char* p = (char*)d_ws;
    auto alloc = [&](size_t bytes) {
        char* r = p;
        p += (bytes + 255) & ~(size_t)255;
        return r;
    };
    float* deg     = (float*)alloc((size_t)N * 4);
    float* dinv    = (float*)alloc((size_t)N * 4);
    int*   rowptr  = (int*)  alloc((size_t)(N + 1) * 4);
    int*   counts  = (int*)  alloc((size_t)N * 4);
    int*   bsums   = (int*)  alloc(256 * 4);
    int*   colIdx  = (int*)  alloc((size_t)E * 4);
    float* valNorm = (float*)alloc((size_t)E * 4);
    unsigned short* bufA = (unsigned short*)alloc((size_t)N * 128 * 2);  // h -> h2 -> enc1
    unsigned short* bufB = (unsigned short*)alloc((size_t)N * 128 * 2);  // h1 -> enc

    const int nbN = (N + TPB - 1) / TPB;
    const int nbE = (E + TPB - 1) / TPB;
    const int nscan = (N + SCAN_CHUNK - 1) / SCAN_CHUNK;
    const int nbM = (N + 127) / 128;

    // CSR build + normalization (f32)
    k_init<<<nbN, TPB, 0, stream>>>(deg, counts, N);
    k_edge_pass1<<<nbE, TPB, 0, stream>>>(dstA, ew, deg, counts, E);
    k_dinv<<<nbN, TPB, 0, stream>>>(deg, dinv, N);
    k_scan_a<<<nscan, TPB, 0, stream>>>(counts, rowptr, bsums, N);
    k_scan_b<<<1, 64, 0, stream>>>(bsums, nscan);
    k_scan_c<<<nbN, TPB, 0, stream>>>(rowptr, bsums, counts, N, E);
    k_fill<<<nbE, TPB, 0, stream>>>(srcA, dstA, ew, dinv, rowptr, counts, colIdx, valNorm, E);

    // h = feat @ W1                       (bufA bf16, ld128)
    k_mgemm<128, 0, false, false><<<nbM, TPB, 0, stream>>>(
        feat, W1, nullptr, bufA, 128, 0, N);
    // h1 = tanh(agg(h) + b1)              (bufB bf16, ld128)
    k_agg<128, 1><<<(N + 3) / 4, TPB, 0, stream>>>(
        bufA, rowptr, colIdx, valNorm, dinv, b1, bufB, 128, N);
    // h2 = h1 @ W2                        (bufA bf16, ld64)
    k_mgemm<64, 0, true, false><<<nbM, TPB, 0, stream>>>(
        bufB, W2, nullptr, bufA, 64, 0, N);
    // enc[:,0:64] = sigmoid(agg(h2) + b2) (bufB bf16, ld128)
    k_agg<64, 2><<<(N + 3) / 4, TPB, 0, stream>>>(
        bufA, rowptr, colIdx, valNorm, dinv, b2, bufB, 128, N);
    // enc[:,64:96] = sigmoid(gdv @ gdvW + gdvB)
    k_gemm_s<73, 32, 4><<<(N + 31) / 32, TPB, 0, stream>>>(
        gdv, 73, gdvW, gdvB, bufB, 128, 64, N);
    // enc[:,96:128] = sigmoid(pr * prW + prB)
    k_pr<<<((size_t)N * 32 + TPB - 1) / TPB, TPB, 0, stream>>>(pr, prW, prB, bufB, N);
    // enc1 = tanh(enc @ eW1 + eB1)        (bufA bf16, ld128)
    k_mgemm<128, 1, true, false><<<nbM, TPB, 0, stream>>>(
        bufB, eW1, eB1, bufA, 128, 0, N);
    // out = enc1 @ eW2 + eB2              (d_out f32)
    k_mgemm<128, 0, true, true><<<nbM, TPB, 0, stream>>>(
        bufA, eW2, eB2, out, 128, 0, N);
}

// Round 4
// 710.035 us; speedup vs baseline: 1.6475x; 1.2899x over previous
//
#include <hip/hip_runtime.h>
#include <hip/hip_bf16.h>
#include <cstdint>
#include <cstddef>

#define TPB 256
#define SCAN_CHUNK 1024

typedef short bf16x8 __attribute__((ext_vector_type(8)));
typedef float f32x4 __attribute__((ext_vector_type(4)));

__device__ __forceinline__ float sigmoidf_(float x) {
    return 1.0f / (1.0f + __expf(-x));
}
__device__ __forceinline__ unsigned short f2bf(float x) {   // RNE
    unsigned u = __float_as_uint(x);
    u += 0x7FFF + ((u >> 16) & 1);
    return (unsigned short)(u >> 16);
}
__device__ __forceinline__ float bf2f(unsigned short b) {
    return __uint_as_float(((unsigned)b) << 16);
}

// async 16B global->LDS: global src is PER-LANE, LDS dest is wave-uniform base
// (HW adds lane*16).  [m97/m104 semantics]
__device__ __forceinline__ void gld_lds16(const void* gsrc, void* ldst) {
    __builtin_amdgcn_global_load_lds(
        (const __attribute__((address_space(1))) unsigned*)gsrc,
        (__attribute__((address_space(3))) unsigned*)ldst, 16, 0, 0);
}

// ---------------------------------------------------------------- graph prep

__global__ __launch_bounds__(TPB) void k_init(float* deg, int* counts, int n) {
    int i = blockIdx.x * TPB + threadIdx.x;
    if (i < n) { deg[i] = 1.0f; counts[i] = 0; }   // self-loop weight 1.0
}

__global__ __launch_bounds__(TPB) void k_edge_pass1(const int* __restrict__ dst,
                                                    const float* __restrict__ ew,
                                                    float* __restrict__ deg,
                                                    int* __restrict__ counts, int E) {
    int e = blockIdx.x * TPB + threadIdx.x;
    if (e < E) {
        int d = dst[e];
        atomicAdd(&deg[d], ew[e]);
        atomicAdd(&counts[d], 1);
    }
}

__global__ __launch_bounds__(TPB) void k_dinv(const float* __restrict__ deg,
                                              float* __restrict__ dinv, int n) {
    int i = blockIdx.x * TPB + threadIdx.x;
    if (i < n) {
        float d = deg[i];
        dinv[i] = (d > 0.0f) ? rsqrtf(d) : 0.0f;
    }
}

__global__ __launch_bounds__(TPB) void k_scan_a(const int* __restrict__ counts,
                                                int* __restrict__ rowptr,
                                                int* __restrict__ bsums, int n) {
    __shared__ int s[SCAN_CHUNK];
    int base = blockIdx.x * SCAN_CHUNK;
    int orig[4];
    #pragma unroll
    for (int j0 = 0; j0 < 4; ++j0) {
        int j = threadIdx.x + j0 * TPB;
        int v = (base + j < n) ? counts[base + j] : 0;
        orig[j0] = v;
        s[j] = v;
    }
    __syncthreads();
    for (int off = 1; off < SCAN_CHUNK; off <<= 1) {
        int t[4];
        #pragma unroll
        for (int j0 = 0; j0 < 4; ++j0) {
            int j = threadIdx.x + j0 * TPB;
            t[j0] = (j >= off) ? s[j - off] : 0;
        }
        __syncthreads();
        #pragma unroll
        for (int j0 = 0; j0 < 4; ++j0) {
            int j = threadIdx.x + j0 * TPB;
            s[j] += t[j0];
        }
        __syncthreads();
    }
    #pragma unroll
    for (int j0 = 0; j0 < 4; ++j0) {
        int j = threadIdx.x + j0 * TPB;
        if (base + j < n) rowptr[base + j] = s[j] - orig[j0];
    }
    if (threadIdx.x == 0) bsums[blockIdx.x] = s[SCAN_CHUNK - 1];
}

// wave/LDS-parallel exclusive scan of bsums[0..nb), nb <= 128; launch <<<1,128>>>
__global__ void k_scan_b(int* bsums, int nb) {
    __shared__ int s[128];
    int t = threadIdx.x;
    int v = (t < nb) ? bsums[t] : 0;
    s[t] = v;
    __syncthreads();
    for (int off = 1; off < 128; off <<= 1) {
        int x = (t >= off) ? s[t - off] : 0;
        __syncthreads();
        s[t] += x;
        __syncthreads();
    }
    if (t < nb) bsums[t] = s[t] - v;   // exclusive
}

__global__ __launch_bounds__(TPB) void k_scan_c(int* __restrict__ rowptr,
                                                const int* __restrict__ bsums,
                                                int* __restrict__ counts, int n, int E) {
    int i = blockIdx.x * TPB + threadIdx.x;
    if (i < n) {
        rowptr[i] += bsums[i / SCAN_CHUNK];
        counts[i] = 0;
    }
    if (i == 0) rowptr[n] = E;
}

__global__ __launch_bounds__(TPB) void k_fill(const int* __restrict__ src,
                                              const int* __restrict__ dst,
                                              const float* __restrict__ ew,
                                              const float* __restrict__ dinv,
                                              const int* __restrict__ rowptr,
                                              int* __restrict__ counts,
                                              int* __restrict__ colIdx,
                                              float* __restrict__ valNorm, int E) {
    int e = blockIdx.x * TPB + threadIdx.x;
    if (e < E) {
        int d = dst[e];
        int s = src[e];
        int pos = atomicAdd(&counts[d], 1);
        int slot = rowptr[d] + pos;
        colIdx[slot] = s;
        valNorm[slot] = dinv[s] * ew[e] * dinv[d];
    }
}

// ---------------------------------------------------------------- aggregation
// one wave per node, h bf16, f32 acc. Unroll-4 gathers for MLP (latency fix).
// ACT: 1 tanh, 2 sigmoid.
template<int D, int ACT>
__global__ __launch_bounds__(TPB) void k_agg(const unsigned short* __restrict__ h,
                                             const int* __restrict__ rowptr,
                                             const int* __restrict__ colIdx,
                                             const float* __restrict__ valNorm,
                                             const float* __restrict__ dinv,
                                             const float* __restrict__ bias,
                                             unsigned short* __restrict__ out,
                                             int ldo, int n) {
    const int lane = threadIdx.x & 63;
    const int node = blockIdx.x * 4 + (threadIdx.x >> 6);
    if (node >= n) return;
    constexpr int PER = D / 64;
    float acc[PER];
    const float di = dinv[node];
    const float sw = di * di;
    if constexpr (PER == 2) {
        unsigned hv = *(const unsigned*)&h[(size_t)node * D + lane * 2];
        acc[0] = bf2f((unsigned short)hv) * sw;
        acc[1] = bf2f((unsigned short)(hv >> 16)) * sw;
    } else {
        acc[0] = bf2f(h[(size_t)node * D + lane]) * sw;
    }
    const int beg = rowptr[node];
    const int end = rowptr[node + 1];
    int e = beg;
    // 4-deep batched gathers: all 4 row-loads issue before any use -> 4x MLP
    for (; e + 4 <= end; e += 4) {
        int ss[4]; float nn[4];
        #pragma unroll
        for (int u = 0; u < 4; ++u) { ss[u] = colIdx[e + u]; nn[u] = valNorm[e + u]; }
        if constexpr (PER == 2) {
            unsigned hv[4];
            #pragma unroll
            for (int u = 0; u < 4; ++u)
                hv[u] = *(const unsigned*)&h[(size_t)ss[u] * D + lane * 2];
            #pragma unroll
            for (int u = 0; u < 4; ++u) {
                acc[0] += bf2f((unsigned short)hv[u]) * nn[u];
                acc[1] += bf2f((unsigned short)(hv[u] >> 16)) * nn[u];
            }
        } else {
            unsigned short hv[4];
            #pragma unroll
            for (int u = 0; u < 4; ++u) hv[u] = h[(size_t)ss[u] * D + lane];
            #pragma unroll
            for (int u = 0; u < 4; ++u) acc[0] += bf2f(hv[u]) * nn[u];
        }
    }
    for (; e < end; ++e) {
        const int s = colIdx[e];
        const float nv = valNorm[e];
        if constexpr (PER == 2) {
            unsigned hv = *(const unsigned*)&h[(size_t)s * D + lane * 2];
            acc[0] += bf2f((unsigned short)hv) * nv;
            acc[1] += bf2f((unsigned short)(hv >> 16)) * nv;
        } else {
            acc[0] += bf2f(h[(size_t)s * D + lane]) * nv;
        }
    }
    if constexpr (PER == 2) {
        float v0 = acc[0] + bias[lane * 2];
        float v1 = acc[1] + bias[lane * 2 + 1];
        if constexpr (ACT == 1) { v0 = tanhf(v0); v1 = tanhf(v1); }
        else                    { v0 = sigmoidf_(v0); v1 = sigmoidf_(v1); }
        unsigned pk = (unsigned)f2bf(v0) | ((unsigned)f2bf(v1) << 16);
        *(unsigned*)&out[(size_t)node * ldo + lane * 2] = pk;
    } else {
        float v = acc[0] + bias[lane];
        v = (ACT == 1) ? tanhf(v) : sigmoidf_(v);
        out[(size_t)node * ldo + lane] = f2bf(v);
    }
}

// ---------------------------------------------------------------- W prep
// Build pre-swizzled bf16 Wt[m][k] from f32 W[k][m]: chunk c covers (m=c>>4,
// k0=(c&15)*8); stored at byte (c*16) ^ ((m&7)<<4).  Once per launch, tiny.
template<int M>
__global__ __launch_bounds__(TPB) void k_prep_w(const float* __restrict__ W,
                                                unsigned short* __restrict__ Wt) {
    int c = blockIdx.x * TPB + threadIdx.x;
    if (c >= M * 16) return;
    int m = c >> 4, k0 = (c & 15) << 3;
    unsigned o[4];
    #pragma unroll
    for (int j = 0; j < 4; ++j) {
        unsigned lo = f2bf(W[(size_t)(k0 + 2 * j) * M + m]);
        unsigned hi = f2bf(W[(size_t)(k0 + 2 * j + 1) * M + m]);
        o[j] = lo | (hi << 16);
    }
    unsigned byte = ((unsigned)c * 16) ^ (unsigned)((m & 7) << 4);
    *(uint4*)((char*)Wt + byte) = *(uint4*)o;
}

// ---------------------------------------------------------------- MFMA GEMM
// C(n x M) = act(A(n x 128) @ W + bias). K=128 one LDS pass. BM=128, 4 waves.
// Wtg pre-swizzled bf16 -> linear async copy. A bf16 -> global_load_lds with
// inverse-XOR source (rule #21: linear dest + inv-swz source + swz read).
template<int M, int ACT, bool A_BF16, bool OUT_F32>
__global__ __launch_bounds__(TPB) void k_mgemm(const void* __restrict__ Ap,
                                               const unsigned short* __restrict__ Wtg,
                                               const float* __restrict__ bias,
                                               void* __restrict__ Cp, int ldc,
                                               int coff, int n) {
    constexpr int K = 128;
    __shared__ __align__(16) unsigned short Al[128 * K];
    __shared__ __align__(16) unsigned short Wt[M * K];

    const int tid = threadIdx.x;
    const int wv = tid >> 6;
    const int ln = tid & 63;
    const int rbase = blockIdx.x * 128;

    // W: linear 1KB-chunk async copies (content already swizzled)
    constexpr int WCH = (M * K * 2) / 1024;
    #pragma unroll
    for (int c = 0; c < WCH / 4; ++c) {
        int cc = wv * (WCH / 4) + c;
        gld_lds16((const char*)Wtg + cc * 1024 + ln * 16, (char*)Wt + cc * 1024);
    }

    if (A_BF16 && rbase + 128 <= n) {
        // full tile: async, linear LDS dest, inverse-swizzled global source
        #pragma unroll
        for (int it = 0; it < 8; ++it) {
            unsigned dbase = (unsigned)(wv * 8 + it) * 1024;
            unsigned d = dbase + (unsigned)ln * 16;
            unsigned row = d >> 8;
            unsigned s = d ^ ((row & 7) << 4);
            gld_lds16((const char*)Ap + (size_t)rbase * 256 + s, (char*)Al + dbase);
        }
    } else {
        // guarded reg-staged path (partial tile or f32 input needing convert)
        for (int ch = tid; ch < 128 * 16; ch += TPB) {
            int row = ch >> 4;
            int col8 = (ch & 15) * 8;
            int r = rbase + row;
            unsigned o4[4] = {0u, 0u, 0u, 0u};
            if (r < n) {
                if constexpr (A_BF16) {
                    uint4 v = *(const uint4*)((const unsigned short*)Ap + (size_t)r * 128 + col8);
                    o4[0] = v.x; o4[1] = v.y; o4[2] = v.z; o4[3] = v.w;
                } else {
                    float4 a = *(const float4*)((const float*)Ap + (size_t)r * 128 + col8);
                    float4 b = *(const float4*)((const float*)Ap + (size_t)r * 128 + col8 + 4);
                    o4[0] = (unsigned)f2bf(a.x) | ((unsigned)f2bf(a.y) << 16);
                    o4[1] = (unsigned)f2bf(a.z) | ((unsigned)f2bf(a.w) << 16);
                    o4[2] = (unsigned)f2bf(b.x) | ((unsigned)f2bf(b.y) << 16);
                    o4[3] = (unsigned)f2bf(b.z) | ((unsigned)f2bf(b.w) << 16);
                }
            }
            unsigned byte = ((unsigned)ch * 16) ^ (unsigned)((row & 7) << 4);
            *(uint4*)((char*)Al + byte) = *(uint4*)o4;
        }
    }
    __syncthreads();   // drains vmcnt (incl. global_load_lds) before barrier

    const int lr = ln & 15;    // A-row / B-col within fragment
    const int lg = ln >> 4;    // k-group

    constexpr int MF = M / 16;
    f32x4 acc[2][MF];
    #pragma unroll
    for (int i = 0; i < 2; ++i)
        #pragma unroll
        for (int j = 0; j < MF; ++j) acc[i][j] = (f32x4){0.f, 0.f, 0.f, 0.f};

    #pragma unroll
    for (int kk = 0; kk < 4; ++kk) {
        const int kb = kk * 64 + lg * 16;
        bf16x8 af[2];
        #pragma unroll
        for (int rf = 0; rf < 2; ++rf) {
            int row = wv * 32 + rf * 16 + lr;
            unsigned byte = (unsigned)(row * 256 + kb) ^ (unsigned)((row & 7) << 4);
            af[rf] = *(bf16x8*)((char*)Al + byte);
        }
        #pragma unroll
        for (int mf = 0; mf < MF; ++mf) {
            int col = mf * 16 + lr;
            unsigned byte = (unsigned)(col * 256 + kb) ^ (unsigned)((col & 7) << 4);
            bf16x8 bfg = *(bf16x8*)((char*)Wt + byte);
            acc[0][mf] = __builtin_amdgcn_mfma_f32_16x16x32_bf16(af[0], bfg, acc[0][mf], 0, 0, 0);
            acc[1][mf] = __builtin_amdgcn_mfma_f32_16x16x32_bf16(af[1], bfg, acc[1][mf], 0, 0, 0);
        }
    }

    // D lane map: col=lane&15, row=(lane>>4)*4+j  [m89-verified]
    #pragma unroll
    for (int rf = 0; rf < 2; ++rf) {
        #pragma unroll
        for (int j = 0; j < 4; ++j) {
            int row = rbase + wv * 32 + rf * 16 + lg * 4 + j;
            if (row < n) {
                #pragma unroll
                for (int mf = 0; mf < MF; ++mf) {
                    int col = mf * 16 + lr;
                    float v = acc[rf][mf][j] + (bias ? bias[col] : 0.0f);
                    if constexpr (ACT == 1) v = tanhf(v);
                    else if constexpr (ACT == 2) v = sigmoidf_(v);
                    if constexpr (OUT_F32)
                        ((float*)Cp)[(size_t)row * ldc + coff + col] = v;
                    else
                        ((unsigned short*)Cp)[(size_t)row * ldc + coff + col] = f2bf(v);
                }
            }
        }
    }
}

// ---------------------------------------------------------------- small SIMT GEMM (gdv)
template<int K, int M, int RI>
__global__ __launch_bounds__(TPB) void k_gemm_s(const float* __restrict__ A, int lda,
                                                const float* __restrict__ W,
                                                const float* __restrict__ bias,
                                                unsigned short* __restrict__ C, int ldc,
                                                int coff, int n) {
    constexpr int TPR = M;
    constexpr int G = TPB / TPR;
    constexpr int RT = G * RI;
    __shared__ float Alds[RT * K];
    __shared__ float Wlds[K * M];
    for (int i = threadIdx.x; i < K * M; i += TPB) Wlds[i] = W[i];

    const int c0 = threadIdx.x % TPR;
    const int rg = threadIdx.x / TPR;
    const int rbase = blockIdx.x * RT;

    for (int i = threadIdx.x; i < RT * K; i += TPB) {
        int rr = i / K;
        int r = rbase + rr;
        Alds[i] = (r < n) ? A[(size_t)r * lda + (i - rr * K)] : 0.0f;
    }
    __syncthreads();

    float acc[RI];
    #pragma unroll
    for (int j = 0; j < RI; ++j) acc[j] = 0.0f;
    const float* Ab = &Alds[rg * RI * K];
    #pragma unroll 4
    for (int k = 0; k < K; ++k) {
        float wv = Wlds[k * M + c0];
        #pragma unroll
        for (int j = 0; j < RI; ++j) acc[j] += Ab[j * K + k] * wv;
    }
    #pragma unroll
    for (int j = 0; j < RI; ++j) {
        int r = rbase + rg * RI + j;
        if (r < n) C[(size_t)r * ldc + coff + c0] = f2bf(sigmoidf_(acc[j] + bias[c0]));
    }
}

__global__ __launch_bounds__(TPB) void k_pr(const float* __restrict__ pr,
                                            const float* __restrict__ prW,
                                            const float* __restrict__ prB,
                                            unsigned short* __restrict__ enc, int n) {
    int i = blockIdx.x * TPB + threadIdx.x;
    if (i < n * 32) {
        int node = i >> 5;
        int c = i & 31;
        float v = pr[node] * prW[c] + prB[c];
        enc[(size_t)node * 128 + 96 + c] = f2bf(sigmoidf_(v));
    }
}

// ---------------------------------------------------------------- launch

extern "C" void kernel_launch(void* const* d_in, const int* in_sizes, int n_in,
                              void* d_out, int out_size, void* d_ws, size_t ws_size,
                              hipStream_t stream) {
    const float* feat = (const float*)d_in[0];
    const float* gdv  = (const float*)d_in[1];
    const float* pr   = (const float*)d_in[2];
    const int*   eidx = (const int*)d_in[3];
    const float* ew   = (const float*)d_in[4];
    const float* W1   = (const float*)d_in[5];
    const float* b1   = (const float*)d_in[6];
    const float* W2   = (const float*)d_in[7];
    const float* b2   = (const float*)d_in[8];
    const float* gdvW = (const float*)d_in[9];
    const float* gdvB = (const float*)d_in[10];
    const float* prW  = (const float*)d_in[11];
    const float* prB  = (const float*)d_in[12];
    const float* eW1  = (const float*)d_in[13];
    const float* eB1  = (const float*)d_in[14];
    const float* eW2  = (const float*)d_in[15];
    const float* eB2  = (const float*)d_in[16];
    float* out = (float*)d_out;

    const int N = in_sizes[0] / 128;
    const int E = in_sizes[4];
    const int* srcA = eidx;
    const int* dstA = eidx + E;

    char* p = (char*)d_ws;
    auto alloc = [&](size_t bytes) {
        char* r = p;
        p += (bytes + 255) & ~(size_t)255;
        return r;
    };
    float* deg     = (float*)alloc((size_t)N * 4);
    float* dinv    = (float*)alloc((size_t)N * 4);
    int*   rowptr  = (int*)  alloc((size_t)(N + 1) * 4);
    int*   counts  = (int*)  alloc((size_t)N * 4);
    int*   bsums   = (int*)  alloc(256 * 4);
    int*   colIdx  = (int*)  alloc((size_t)E * 4);
    float* valNorm = (float*)alloc((size_t)E * 4);
    unsigned short* wt1  = (unsigned short*)alloc(128 * 128 * 2);
    unsigned short* wt2  = (unsigned short*)alloc(128 * 64 * 2);
    unsigned short* wtE1 = (unsigned short*)alloc(128 * 128 * 2);
    unsigned short* wtE2 = (unsigned short*)alloc(128 * 128 * 2);
    unsigned short* bufA = (unsigned short*)alloc((size_t)N * 128 * 2);  // h -> h2 -> enc1
    unsigned short* bufB = (unsigned short*)alloc((size_t)N * 128 * 2);  // h1 -> enc

    const int nbN = (N + TPB - 1) / TPB;
    const int nbE = (E + TPB - 1) / TPB;
    const int nscan = (N + SCAN_CHUNK - 1) / SCAN_CHUNK;
    const int nbM = (N + 127) / 128;

    // weight prep (independent of CSR)
    k_prep_w<128><<<8, TPB, 0, stream>>>(W1, wt1);
    k_prep_w<64><<<4, TPB, 0, stream>>>(W2, wt2);
    k_prep_w<128><<<8, TPB, 0, stream>>>(eW1, wtE1);
    k_prep_w<128><<<8, TPB, 0, stream>>>(eW2, wtE2);

    // CSR build + normalization (f32)
    k_init<<<nbN, TPB, 0, stream>>>(deg, counts, N);
    k_edge_pass1<<<nbE, TPB, 0, stream>>>(dstA, ew, deg, counts, E);
    k_dinv<<<nbN, TPB, 0, stream>>>(deg, dinv, N);
    k_scan_a<<<nscan, TPB, 0, stream>>>(counts, rowptr, bsums, N);
    k_scan_b<<<1, 128, 0, stream>>>(bsums, nscan);
    k_scan_c<<<nbN, TPB, 0, stream>>>(rowptr, bsums, counts, N, E);
    k_fill<<<nbE, TPB, 0, stream>>>(srcA, dstA, ew, dinv, rowptr, counts, colIdx, valNorm, E);

    // h = feat @ W1                       (bufA bf16, ld128)
    k_mgemm<128, 0, false, false><<<nbM, TPB, 0, stream>>>(
        feat, wt1, nullptr, bufA, 128, 0, N);
    // h1 = tanh(agg(h) + b1)              (bufB bf16, ld128)
    k_agg<128, 1><<<(N + 3) / 4, TPB, 0, stream>>>(
        bufA, rowptr, colIdx, valNorm, dinv, b1, bufB, 128, N);
    // h2 = h1 @ W2                        (bufA bf16, ld64)
    k_mgemm<64, 0, true, false><<<nbM, TPB, 0, stream>>>(
        bufB, wt2, nullptr, bufA, 64, 0, N);
    // enc[:,0:64] = sigmoid(agg(h2) + b2) (bufB bf16, ld128)
    k_agg<64, 2><<<(N + 3) / 4, TPB, 0, stream>>>(
        bufA, rowptr, colIdx, valNorm, dinv, b2, bufB, 128, N);
    // enc[:,64:96] = sigmoid(gdv @ gdvW + gdvB)
    k_gemm_s<73, 32, 4><<<(N + 31) / 32, TPB, 0, stream>>>(
        gdv, 73, gdvW, gdvB, bufB, 128, 64, N);
    // enc[:,96:128] = sigmoid(pr * prW + prB)
    k_pr<<<((size_t)N * 32 + TPB - 1) / TPB, TPB, 0, stream>>>(pr, prW, prB, bufB, N);
    // enc1 = tanh(enc @ eW1 + eB1)        (bufA bf16, ld128)
    k_mgemm<128, 1, true, false><<<nbM, TPB, 0, stream>>>(
        bufB, wtE1, eB1, bufA, 128, 0, N);
    // out = enc1 @ eW2 + eB2              (d_out f32)
    k_mgemm<128, 0, true, true><<<nbM, TPB, 0, stream>>>(
        bufA, wtE2, eB2, out, 128, 0, N);
}

// Round 5
// 687.987 us; speedup vs baseline: 1.7003x; 1.0320x over previous
//
#include <hip/hip_runtime.h>
#include <hip/hip_bf16.h>
#include <cstdint>
#include <cstddef>

#define TPB 256
#define SCAN_CHUNK 1024
#define NXCD 8

typedef short bf16x8 __attribute__((ext_vector_type(8)));
typedef float f32x4 __attribute__((ext_vector_type(4)));

__device__ __forceinline__ float sigmoidf_(float x) {
    return 1.0f / (1.0f + __expf(-x));
}
__device__ __forceinline__ unsigned short f2bf(float x) {   // RNE
    unsigned u = __float_as_uint(x);
    u += 0x7FFF + ((u >> 16) & 1);
    return (unsigned short)(u >> 16);
}
__device__ __forceinline__ float bf2f(unsigned short b) {
    return __uint_as_float(((unsigned)b) << 16);
}
// physical XCD id of this wave [m09: 0..7 on MI355X]
__device__ __forceinline__ unsigned xcc_id() {
    unsigned x;
    asm volatile("s_getreg_b32 %0, hwreg(HW_REG_XCC_ID)" : "=s"(x));
    return x & (NXCD - 1);
}

// async 16B global->LDS: global src is PER-LANE, LDS dest is wave-uniform base
__device__ __forceinline__ void gld_lds16(const void* gsrc, void* ldst) {
    __builtin_amdgcn_global_load_lds(
        (const __attribute__((address_space(1))) unsigned*)gsrc,
        (__attribute__((address_space(3))) unsigned*)ldst, 16, 0, 0);
}

// ---------------------------------------------------------------- graph prep

__global__ __launch_bounds__(TPB) void k_zero8(float* deg8, unsigned* counts8, int n8) {
    int i = blockIdx.x * TPB + threadIdx.x;
    if (i < n8) { deg8[i] = 0.0f; counts8[i] = 0u; }
}

// XCD-private histogram: atomics stay in this XCD's L2 (copy touched only by
// waves physically resident here -> L2 atomicity suffices; no memory-side RMW).
__global__ __launch_bounds__(TPB) void k_pass1(const int* __restrict__ dst,
                                               const float* __restrict__ ew,
                                               float* __restrict__ deg8,
                                               unsigned* __restrict__ counts8,
                                               unsigned* __restrict__ epos,
                                               int E, int N) {
    int e = blockIdx.x * TPB + threadIdx.x;
    if (e < E) {
        unsigned c = xcc_id();
        int d = dst[e];
        __hip_atomic_fetch_add(&deg8[(size_t)c * N + d], ew[e],
                               __ATOMIC_RELAXED, __HIP_MEMORY_SCOPE_WORKGROUP);
        unsigned pos = __hip_atomic_fetch_add(&counts8[(size_t)c * N + d], 1u,
                               __ATOMIC_RELAXED, __HIP_MEMORY_SCOPE_WORKGROUP);
        epos[e] = pos | (c << 28);
    }
}

// per node: deg total (+1 self-loop) -> dinv; per-XCD exclusive bases into
// counts8; total into counts (scan input).
__global__ __launch_bounds__(TPB) void k_reduce(const float* __restrict__ deg8,
                                                unsigned* __restrict__ counts8,
                                                float* __restrict__ dinv,
                                                int* __restrict__ counts, int n) {
    int i = blockIdx.x * TPB + threadIdx.x;
    if (i >= n) return;
    float s = 1.0f;
    #pragma unroll
    for (int c = 0; c < NXCD; ++c) s += deg8[(size_t)c * n + i];
    dinv[i] = rsqrtf(s);                       // s >= 1
    unsigned run = 0;
    #pragma unroll
    for (int c = 0; c < NXCD; ++c) {
        unsigned v = counts8[(size_t)c * n + i];
        counts8[(size_t)c * n + i] = run;      // exclusive base per XCD
        run += v;
    }
    counts[i] = (int)run;
}

__global__ __launch_bounds__(TPB) void k_scan_a(const int* __restrict__ counts,
                                                int* __restrict__ rowptr,
                                                int* __restrict__ bsums, int n) {
    __shared__ int s[SCAN_CHUNK];
    int base = blockIdx.x * SCAN_CHUNK;
    int orig[4];
    #pragma unroll
    for (int j0 = 0; j0 < 4; ++j0) {
        int j = threadIdx.x + j0 * TPB;
        int v = (base + j < n) ? counts[base + j] : 0;
        orig[j0] = v;
        s[j] = v;
    }
    __syncthreads();
    for (int off = 1; off < SCAN_CHUNK; off <<= 1) {
        int t[4];
        #pragma unroll
        for (int j0 = 0; j0 < 4; ++j0) {
            int j = threadIdx.x + j0 * TPB;
            t[j0] = (j >= off) ? s[j - off] : 0;
        }
        __syncthreads();
        #pragma unroll
        for (int j0 = 0; j0 < 4; ++j0) {
            int j = threadIdx.x + j0 * TPB;
            s[j] += t[j0];
        }
        __syncthreads();
    }
    #pragma unroll
    for (int j0 = 0; j0 < 4; ++j0) {
        int j = threadIdx.x + j0 * TPB;
        if (base + j < n) rowptr[base + j] = s[j] - orig[j0];
    }
    if (threadIdx.x == 0) bsums[blockIdx.x] = s[SCAN_CHUNK - 1];
}

__global__ void k_scan_b(int* bsums, int nb) {   // <<<1,128>>>
    __shared__ int s[128];
    int t = threadIdx.x;
    int v = (t < nb) ? bsums[t] : 0;
    s[t] = v;
    __syncthreads();
    for (int off = 1; off < 128; off <<= 1) {
        int x = (t >= off) ? s[t - off] : 0;
        __syncthreads();
        s[t] += x;
        __syncthreads();
    }
    if (t < nb) bsums[t] = s[t] - v;
}

// finalize rowptr; fold rowptr into the per-XCD bases (fill is then atomic-free)
__global__ __launch_bounds__(TPB) void k_scan_c(int* __restrict__ rowptr,
                                                const int* __restrict__ bsums,
                                                unsigned* __restrict__ counts8,
                                                int n, int E) {
    int i = blockIdx.x * TPB + threadIdx.x;
    if (i < n) {
        int rp = rowptr[i] + bsums[i / SCAN_CHUNK];
        rowptr[i] = rp;
        #pragma unroll
        for (int c = 0; c < NXCD; ++c) counts8[(size_t)c * n + i] += (unsigned)rp;
    }
    if (i == 0) rowptr[n] = E;
}

__global__ __launch_bounds__(TPB) void k_fill(const int* __restrict__ src,
                                              const int* __restrict__ dst,
                                              const float* __restrict__ ew,
                                              const float* __restrict__ dinv,
                                              const unsigned* __restrict__ counts8,
                                              const unsigned* __restrict__ epos,
                                              int* __restrict__ colIdx,
                                              float* __restrict__ valNorm,
                                              int E, int N) {
    int e = blockIdx.x * TPB + threadIdx.x;
    if (e < E) {
        int d = dst[e];
        int s = src[e];
        unsigned ep = epos[e];
        unsigned slot = counts8[(size_t)(ep >> 28) * N + d] + (ep & 0x0FFFFFFFu);
        colIdx[slot] = s;
        valNorm[slot] = dinv[s] * ew[e] * dinv[d];
    }
}

// ---------------------------------------------------------------- aggregation
// one wave per node, h bf16, f32 acc. 8-deep clamped gather batches (latency
// -bound: padded parallel loads beat serial tails). ACT: 1 tanh, 2 sigmoid.
template<int D, int ACT>
__global__ __launch_bounds__(TPB) void k_agg(const unsigned short* __restrict__ h,
                                             const int* __restrict__ rowptr,
                                             const int* __restrict__ colIdx,
                                             const float* __restrict__ valNorm,
                                             const float* __restrict__ dinv,
                                             const float* __restrict__ bias,
                                             unsigned short* __restrict__ out,
                                             int ldo, int n) {
    const int lane = threadIdx.x & 63;
    const int node = blockIdx.x * 4 + (threadIdx.x >> 6);
    if (node >= n) return;
    constexpr int PER = D / 64;
    float acc[PER];
    const float di = dinv[node];
    const float sw = di * di;
    if constexpr (PER == 2) {
        unsigned hv = *(const unsigned*)&h[(size_t)node * D + lane * 2];
        acc[0] = bf2f((unsigned short)hv) * sw;
        acc[1] = bf2f((unsigned short)(hv >> 16)) * sw;
    } else {
        acc[0] = bf2f(h[(size_t)node * D + lane]) * sw;
    }
    const int beg = rowptr[node];
    const int end = rowptr[node + 1];
    for (int e = beg; e < end; e += 8) {
        int ss[8]; float nn[8];
        #pragma unroll
        for (int u = 0; u < 8; ++u) {
            int idx = e + u;
            int cl = idx < end ? idx : (end - 1);
            ss[u] = colIdx[cl];                       // wave-uniform scalar load
            nn[u] = idx < end ? valNorm[cl] : 0.0f;
        }
        if constexpr (PER == 2) {
            unsigned hv[8];
            #pragma unroll
            for (int u = 0; u < 8; ++u)
                hv[u] = *(const unsigned*)&h[(size_t)ss[u] * D + lane * 2];
            #pragma unroll
            for (int u = 0; u < 8; ++u) {
                acc[0] += bf2f((unsigned short)hv[u]) * nn[u];
                acc[1] += bf2f((unsigned short)(hv[u] >> 16)) * nn[u];
            }
        } else {
            unsigned short hv[8];
            #pragma unroll
            for (int u = 0; u < 8; ++u) hv[u] = h[(size_t)ss[u] * D + lane];
            #pragma unroll
            for (int u = 0; u < 8; ++u) acc[0] += bf2f(hv[u]) * nn[u];
        }
    }
    if constexpr (PER == 2) {
        float v0 = acc[0] + bias[lane * 2];
        float v1 = acc[1] + bias[lane * 2 + 1];
        if constexpr (ACT == 1) { v0 = tanhf(v0); v1 = tanhf(v1); }
        else                    { v0 = sigmoidf_(v0); v1 = sigmoidf_(v1); }
        unsigned pk = (unsigned)f2bf(v0) | ((unsigned)f2bf(v1) << 16);
        *(unsigned*)&out[(size_t)node * ldo + lane * 2] = pk;
    } else {
        float v = acc[0] + bias[lane];
        v = (ACT == 1) ? tanhf(v) : sigmoidf_(v);
        out[(size_t)node * ldo + lane] = f2bf(v);
    }
}

// ---------------------------------------------------------------- W prep
template<int M>
__global__ __launch_bounds__(TPB) void k_prep_w(const float* __restrict__ W,
                                                unsigned short* __restrict__ Wt) {
    int c = blockIdx.x * TPB + threadIdx.x;
    if (c >= M * 16) return;
    int m = c >> 4, k0 = (c & 15) << 3;
    unsigned o[4];
    #pragma unroll
    for (int j = 0; j < 4; ++j) {
        unsigned lo = f2bf(W[(size_t)(k0 + 2 * j) * M + m]);
        unsigned hi = f2bf(W[(size_t)(k0 + 2 * j + 1) * M + m]);
        o[j] = lo | (hi << 16);
    }
    unsigned byte = ((unsigned)c * 16) ^ (unsigned)((m & 7) << 4);
    *(uint4*)((char*)Wt + byte) = *(uint4*)o;
}

// ---------------------------------------------------------------- MFMA GEMM
template<int M, int ACT, bool A_BF16, bool OUT_F32>
__global__ __launch_bounds__(TPB) void k_mgemm(const void* __restrict__ Ap,
                                               const unsigned short* __restrict__ Wtg,
                                               const float* __restrict__ bias,
                                               void* __restrict__ Cp, int ldc,
                                               int coff, int n) {
    constexpr int K = 128;
    __shared__ __align__(16) unsigned short Al[128 * K];
    __shared__ __align__(16) unsigned short Wt[M * K];

    const int tid = threadIdx.x;
    const int wv = tid >> 6;
    const int ln = tid & 63;
    const int rbase = blockIdx.x * 128;

    constexpr int WCH = (M * K * 2) / 1024;
    #pragma unroll
    for (int c = 0; c < WCH / 4; ++c) {
        int cc = wv * (WCH / 4) + c;
        gld_lds16((const char*)Wtg + cc * 1024 + ln * 16, (char*)Wt + cc * 1024);
    }

    if (A_BF16 && rbase + 128 <= n) {
        #pragma unroll
        for (int it = 0; it < 8; ++it) {
            unsigned dbase = (unsigned)(wv * 8 + it) * 1024;
            unsigned d = dbase + (unsigned)ln * 16;
            unsigned row = d >> 8;
            unsigned s = d ^ ((row & 7) << 4);
            gld_lds16((const char*)Ap + (size_t)rbase * 256 + s, (char*)Al + dbase);
        }
    } else {
        for (int ch = tid; ch < 128 * 16; ch += TPB) {
            int row = ch >> 4;
            int col8 = (ch & 15) * 8;
            int r = rbase + row;
            unsigned o4[4] = {0u, 0u, 0u, 0u};
            if (r < n) {
                if constexpr (A_BF16) {
                    uint4 v = *(const uint4*)((const unsigned short*)Ap + (size_t)r * 128 + col8);
                    o4[0] = v.x; o4[1] = v.y; o4[2] = v.z; o4[3] = v.w;
                } else {
                    float4 a = *(const float4*)((const float*)Ap + (size_t)r * 128 + col8);
                    float4 b = *(const float4*)((const float*)Ap + (size_t)r * 128 + col8 + 4);
                    o4[0] = (unsigned)f2bf(a.x) | ((unsigned)f2bf(a.y) << 16);
                    o4[1] = (unsigned)f2bf(a.z) | ((unsigned)f2bf(a.w) << 16);
                    o4[2] = (unsigned)f2bf(b.x) | ((unsigned)f2bf(b.y) << 16);
                    o4[3] = (unsigned)f2bf(b.z) | ((unsigned)f2bf(b.w) << 16);
                }
            }
            unsigned byte = ((unsigned)ch * 16) ^ (unsigned)((row & 7) << 4);
            *(uint4*)((char*)Al + byte) = *(uint4*)o4;
        }
    }
    __syncthreads();

    const int lr = ln & 15;
    const int lg = ln >> 4;

    constexpr int MF = M / 16;
    f32x4 acc[2][MF];
    #pragma unroll
    for (int i = 0; i < 2; ++i)
        #pragma unroll
        for (int j = 0; j < MF; ++j) acc[i][j] = (f32x4){0.f, 0.f, 0.f, 0.f};

    #pragma unroll
    for (int kk = 0; kk < 4; ++kk) {
        const int kb = kk * 64 + lg * 16;
        bf16x8 af[2];
        #pragma unroll
        for (int rf = 0; rf < 2; ++rf) {
            int row = wv * 32 + rf * 16 + lr;
            unsigned byte = (unsigned)(row * 256 + kb) ^ (unsigned)((row & 7) << 4);
            af[rf] = *(bf16x8*)((char*)Al + byte);
        }
        #pragma unroll
        for (int mf = 0; mf < MF; ++mf) {
            int col = mf * 16 + lr;
            unsigned byte = (unsigned)(col * 256 + kb) ^ (unsigned)((col & 7) << 4);
            bf16x8 bfg = *(bf16x8*)((char*)Wt + byte);
            acc[0][mf] = __builtin_amdgcn_mfma_f32_16x16x32_bf16(af[0], bfg, acc[0][mf], 0, 0, 0);
            acc[1][mf] = __builtin_amdgcn_mfma_f32_16x16x32_bf16(af[1], bfg, acc[1][mf], 0, 0, 0);
        }
    }

    #pragma unroll
    for (int rf = 0; rf < 2; ++rf) {
        #pragma unroll
        for (int j = 0; j < 4; ++j) {
            int row = rbase + wv * 32 + rf * 16 + lg * 4 + j;
            if (row < n) {
                #pragma unroll
                for (int mf = 0; mf < MF; ++mf) {
                    int col = mf * 16 + lr;
                    float v = acc[rf][mf][j] + (bias ? bias[col] : 0.0f);
                    if constexpr (ACT == 1) v = tanhf(v);
                    else if constexpr (ACT == 2) v = sigmoidf_(v);
                    if constexpr (OUT_F32)
                        ((float*)Cp)[(size_t)row * ldc + coff + col] = v;
                    else
                        ((unsigned short*)Cp)[(size_t)row * ldc + coff + col] = f2bf(v);
                }
            }
        }
    }
}

// ---------------------------------------------------------------- small SIMT GEMM (gdv)
template<int K, int M, int RI>
__global__ __launch_bounds__(TPB) void k_gemm_s(const float* __restrict__ A, int lda,
                                                const float* __restrict__ W,
                                                const float* __restrict__ bias,
                                                unsigned short* __restrict__ C, int ldc,
                                                int coff, int n) {
    constexpr int TPR = M;
    constexpr int G = TPB / TPR;
    constexpr int RT = G * RI;
    __shared__ float Alds[RT * K];
    __shared__ float Wlds[K * M];
    for (int i = threadIdx.x; i < K * M; i += TPB) Wlds[i] = W[i];

    const int c0 = threadIdx.x % TPR;
    const int rg = threadIdx.x / TPR;
    const int rbase = blockIdx.x * RT;

    for (int i = threadIdx.x; i < RT * K; i += TPB) {
        int rr = i / K;
        int r = rbase + rr;
        Alds[i] = (r < n) ? A[(size_t)r * lda + (i - rr * K)] : 0.0f;
    }
    __syncthreads();

    float acc[RI];
    #pragma unroll
    for (int j = 0; j < RI; ++j) acc[j] = 0.0f;
    const float* Ab = &Alds[rg * RI * K];
    #pragma unroll 4
    for (int k = 0; k < K; ++k) {
        float wv = Wlds[k * M + c0];
        #pragma unroll
        for (int j = 0; j < RI; ++j) acc[j] += Ab[j * K + k] * wv;
    }
    #pragma unroll
    for (int j = 0; j < RI; ++j) {
        int r = rbase + rg * RI + j;
        if (r < n) C[(size_t)r * ldc + coff + c0] = f2bf(sigmoidf_(acc[j] + bias[c0]));
    }
}

__global__ __launch_bounds__(TPB) void k_pr(const float* __restrict__ pr,
                                            const float* __restrict__ prW,
                                            const float* __restrict__ prB,
                                            unsigned short* __restrict__ enc, int n) {
    int i = blockIdx.x * TPB + threadIdx.x;
    if (i < n * 32) {
        int node = i >> 5;
        int c = i & 31;
        float v = pr[node] * prW[c] + prB[c];
        enc[(size_t)node * 128 + 96 + c] = f2bf(sigmoidf_(v));
    }
}

// ---------------------------------------------------------------- launch

extern "C" void kernel_launch(void* const* d_in, const int* in_sizes, int n_in,
                              void* d_out, int out_size, void* d_ws, size_t ws_size,
                              hipStream_t stream) {
    const float* feat = (const float*)d_in[0];
    const float* gdv  = (const float*)d_in[1];
    const float* pr   = (const float*)d_in[2];
    const int*   eidx = (const int*)d_in[3];
    const float* ew   = (const float*)d_in[4];
    const float* W1   = (const float*)d_in[5];
    const float* b1   = (const float*)d_in[6];
    const float* W2   = (const float*)d_in[7];
    const float* b2   = (const float*)d_in[8];
    const float* gdvW = (const float*)d_in[9];
    const float* gdvB = (const float*)d_in[10];
    const float* prW  = (const float*)d_in[11];
    const float* prB  = (const float*)d_in[12];
    const float* eW1  = (const float*)d_in[13];
    const float* eB1  = (const float*)d_in[14];
    const float* eW2  = (const float*)d_in[15];
    const float* eB2  = (const float*)d_in[16];
    float* out = (float*)d_out;

    const int N = in_sizes[0] / 128;
    const int E = in_sizes[4];
    const int* srcA = eidx;
    const int* dstA = eidx + E;

    char* p = (char*)d_ws;
    auto alloc = [&](size_t bytes) {
        char* r = p;
        p += (bytes + 255) & ~(size_t)255;
        return r;
    };
    float*    deg8    = (float*)   alloc((size_t)NXCD * N * 4);
    unsigned* counts8 = (unsigned*)alloc((size_t)NXCD * N * 4);
    unsigned* epos    = (unsigned*)alloc((size_t)E * 4);
    float*    dinv    = (float*)   alloc((size_t)N * 4);
    int*      rowptr  = (int*)     alloc((size_t)(N + 1) * 4);
    int*      counts  = (int*)     alloc((size_t)N * 4);
    int*      bsums   = (int*)     alloc(256 * 4);
    int*      colIdx  = (int*)     alloc((size_t)E * 4);
    float*    valNorm = (float*)   alloc((size_t)E * 4);
    unsigned short* wt1  = (unsigned short*)alloc(128 * 128 * 2);
    unsigned short* wt2  = (unsigned short*)alloc(128 * 64 * 2);
    unsigned short* wtE1 = (unsigned short*)alloc(128 * 128 * 2);
    unsigned short* wtE2 = (unsigned short*)alloc(128 * 128 * 2);
    unsigned short* bufA = (unsigned short*)alloc((size_t)N * 128 * 2);  // h -> h2 -> enc1
    unsigned short* bufB = (unsigned short*)alloc((size_t)N * 128 * 2);  // h1 -> enc

    const int nbN = (N + TPB - 1) / TPB;
    const int nbE = (E + TPB - 1) / TPB;
    const int nb8 = (NXCD * N + TPB - 1) / TPB;
    const int nscan = (N + SCAN_CHUNK - 1) / SCAN_CHUNK;
    const int nbM = (N + 127) / 128;

    // weight prep (independent of CSR)
    k_prep_w<128><<<8, TPB, 0, stream>>>(W1, wt1);
    k_prep_w<64><<<4, TPB, 0, stream>>>(W2, wt2);
    k_prep_w<128><<<8, TPB, 0, stream>>>(eW1, wtE1);
    k_prep_w<128><<<8, TPB, 0, stream>>>(eW2, wtE2);

    // CSR build + normalization
    k_zero8<<<nb8, TPB, 0, stream>>>(deg8, counts8, NXCD * N);
    k_pass1<<<nbE, TPB, 0, stream>>>(dstA, ew, deg8, counts8, epos, E, N);
    k_reduce<<<nbN, TPB, 0, stream>>>(deg8, counts8, dinv, counts, N);
    k_scan_a<<<nscan, TPB, 0, stream>>>(counts, rowptr, bsums, N);
    k_scan_b<<<1, 128, 0, stream>>>(bsums, nscan);
    k_scan_c<<<nbN, TPB, 0, stream>>>(rowptr, bsums, counts8, N, E);
    k_fill<<<nbE, TPB, 0, stream>>>(srcA, dstA, ew, dinv, counts8, epos, colIdx, valNorm, E, N);

    // h = feat @ W1                       (bufA bf16, ld128)
    k_mgemm<128, 0, false, false><<<nbM, TPB, 0, stream>>>(
        feat, wt1, nullptr, bufA, 128, 0, N);
    // h1 = tanh(agg(h) + b1)              (bufB bf16, ld128)
    k_agg<128, 1><<<(N + 3) / 4, TPB, 0, stream>>>(
        bufA, rowptr, colIdx, valNorm, dinv, b1, bufB, 128, N);
    // h2 = h1 @ W2                        (bufA bf16, ld64)
    k_mgemm<64, 0, true, false><<<nbM, TPB, 0, stream>>>(
        bufB, wt2, nullptr, bufA, 64, 0, N);
    // enc[:,0:64] = sigmoid(agg(h2) + b2) (bufB bf16, ld128)
    k_agg<64, 2><<<(N + 3) / 4, TPB, 0, stream>>>(
        bufA, rowptr, colIdx, valNorm, dinv, b2, bufB, 128, N);
    // enc[:,64:96] = sigmoid(gdv @ gdvW + gdvB)
    k_gemm_s<73, 32, 4><<<(N + 31) / 32, TPB, 0, stream>>>(
        gdv, 73, gdvW, gdvB, bufB, 128, 64, N);
    // enc[:,96:128] = sigmoid(pr * prW + prB)
    k_pr<<<((size_t)N * 32 + TPB - 1) / TPB, TPB, 0, stream>>>(pr, prW, prB, bufB, N);
    // enc1 = tanh(enc @ eW1 + eB1)        (bufA bf16, ld128)
    k_mgemm<128, 1, true, false><<<nbM, TPB, 0, stream>>>(
        bufB, wtE1, eB1, bufA, 128, 0, N);
    // out = enc1 @ eW2 + eB2              (d_out f32)
    k_mgemm<128, 0, true, true><<<nbM, TPB, 0, stream>>>(
        bufA, wtE2, eB2, out, 128, 0, N);
}

// Round 6
// 599.702 us; speedup vs baseline: 1.9506x; 1.1472x over previous
//
#include <hip/hip_runtime.h>
#include <hip/hip_bf16.h>
#include <cstdint>
#include <cstddef>

#define TPB 256
#define SCAN_CHUNK 1024

typedef short bf16x8 __attribute__((ext_vector_type(8)));
typedef float f32x4 __attribute__((ext_vector_type(4)));

__device__ __forceinline__ float sigmoidf_(float x) {
    return 1.0f / (1.0f + __expf(-x));
}
__device__ __forceinline__ unsigned short f2bf(float x) {   // RNE
    unsigned u = __float_as_uint(x);
    u += 0x7FFF + ((u >> 16) & 1);
    return (unsigned short)(u >> 16);
}
__device__ __forceinline__ float bf2f(unsigned short b) {
    return __uint_as_float(((unsigned)b) << 16);
}

// async 16B global->LDS: global src is PER-LANE, LDS dest is wave-uniform base
__device__ __forceinline__ void gld_lds16(const void* gsrc, void* ldst) {
    __builtin_amdgcn_global_load_lds(
        (const __attribute__((address_space(1))) unsigned*)gsrc,
        (__attribute__((address_space(3))) unsigned*)ldst, 16, 0, 0);
}

// ---------------------------------------------------------------- graph prep

__global__ __launch_bounds__(TPB) void k_zero(unsigned* counts, int n) {
    int i = blockIdx.x * TPB + threadIdx.x;
    if (i < n) counts[i] = 0u;
}

// ONE returning atomic per edge (memory-side RMW is the ceiling: ~20G atomics/s)
__global__ __launch_bounds__(TPB) void k_pass1(const int* __restrict__ dst,
                                               unsigned* __restrict__ counts,
                                               unsigned* __restrict__ epos, int E) {
    int e = blockIdx.x * TPB + threadIdx.x;
    if (e < E) epos[e] = atomicAdd(&counts[dst[e]], 1u);
}

__global__ __launch_bounds__(TPB) void k_scan_a(const unsigned* __restrict__ counts,
                                                int* __restrict__ rowptr,
                                                int* __restrict__ bsums, int n) {
    __shared__ int s[SCAN_CHUNK];
    int base = blockIdx.x * SCAN_CHUNK;
    int orig[4];
    #pragma unroll
    for (int j0 = 0; j0 < 4; ++j0) {
        int j = threadIdx.x + j0 * TPB;
        int v = (base + j < n) ? (int)counts[base + j] : 0;
        orig[j0] = v;
        s[j] = v;
    }
    __syncthreads();
    for (int off = 1; off < SCAN_CHUNK; off <<= 1) {
        int t[4];
        #pragma unroll
        for (int j0 = 0; j0 < 4; ++j0) {
            int j = threadIdx.x + j0 * TPB;
            t[j0] = (j >= off) ? s[j - off] : 0;
        }
        __syncthreads();
        #pragma unroll
        for (int j0 = 0; j0 < 4; ++j0) {
            int j = threadIdx.x + j0 * TPB;
            s[j] += t[j0];
        }
        __syncthreads();
    }
    #pragma unroll
    for (int j0 = 0; j0 < 4; ++j0) {
        int j = threadIdx.x + j0 * TPB;
        if (base + j < n) rowptr[base + j] = s[j] - orig[j0];
    }
    if (threadIdx.x == 0) bsums[blockIdx.x] = s[SCAN_CHUNK - 1];
}

__global__ void k_scan_b(int* bsums, int nb) {   // <<<1,128>>>
    __shared__ int s[128];
    int t = threadIdx.x;
    int v = (t < nb) ? bsums[t] : 0;
    s[t] = v;
    __syncthreads();
    for (int off = 1; off < 128; off <<= 1) {
        int x = (t >= off) ? s[t - off] : 0;
        __syncthreads();
        s[t] += x;
        __syncthreads();
    }
    if (t < nb) bsums[t] = s[t] - v;
}

__global__ __launch_bounds__(TPB) void k_scan_c(int* __restrict__ rowptr,
                                                const int* __restrict__ bsums,
                                                int n, int E) {
    int i = blockIdx.x * TPB + threadIdx.x;
    if (i < n) rowptr[i] += bsums[i / SCAN_CHUNK];
    if (i == 0) rowptr[n] = E;
}

// atomic-free fill: slot from scan + per-edge pos; store raw edge weight
__global__ __launch_bounds__(TPB) void k_fill(const int* __restrict__ src,
                                              const int* __restrict__ dst,
                                              const float* __restrict__ ew,
                                              const int* __restrict__ rowptr,
                                              const unsigned* __restrict__ epos,
                                              int* __restrict__ colIdx,
                                              float* __restrict__ valNorm, int E) {
    int e = blockIdx.x * TPB + threadIdx.x;
    if (e < E) {
        unsigned slot = (unsigned)rowptr[dst[e]] + epos[e];
        colIdx[slot] = src[e];
        valNorm[slot] = ew[e];
    }
}

// deg = 1 + sum of row's raw weights (coalesced-ish segmented sum); dinv=rsqrt
__global__ __launch_bounds__(TPB) void k_deg(const int* __restrict__ rowptr,
                                             const float* __restrict__ valRaw,
                                             float* __restrict__ dinv, int n) {
    int i = blockIdx.x * TPB + threadIdx.x;
    if (i >= n) return;
    int beg = rowptr[i], end = rowptr[i + 1];
    float s = 1.0f;
    for (int e = beg; e < end; ++e) s += valRaw[e];
    dinv[i] = rsqrtf(s);    // s >= 1
}

// valNorm[slot] = dinv[src] * ew  (dst factor folded into agg epilogue)
__global__ __launch_bounds__(TPB) void k_scale(const int* __restrict__ colIdx,
                                               const float* __restrict__ dinv,
                                               float* __restrict__ valNorm, int E) {
    int e = blockIdx.x * TPB + threadIdx.x;
    if (e < E) valNorm[e] *= dinv[colIdx[e]];
}

// ---------------------------------------------------------------- aggregation
// one wave per node, h bf16, f32 acc. 8-deep clamped gather batches.
// out = dinv_d*(dinv_d*h_d + sum nv*h_s) + bias.  ACT: 1 tanh, 2 sigmoid.
template<int D, int ACT>
__global__ __launch_bounds__(TPB) void k_agg(const unsigned short* __restrict__ h,
                                             const int* __restrict__ rowptr,
                                             const int* __restrict__ colIdx,
                                             const float* __restrict__ valNorm,
                                             const float* __restrict__ dinv,
                                             const float* __restrict__ bias,
                                             unsigned short* __restrict__ out,
                                             int ldo, int n) {
    const int lane = threadIdx.x & 63;
    const int node = blockIdx.x * 4 + (threadIdx.x >> 6);
    if (node >= n) return;
    constexpr int PER = D / 64;
    float acc[PER];
    const float di = dinv[node];
    if constexpr (PER == 2) {
        unsigned hv = *(const unsigned*)&h[(size_t)node * D + lane * 2];
        acc[0] = bf2f((unsigned short)hv) * di;
        acc[1] = bf2f((unsigned short)(hv >> 16)) * di;
    } else {
        acc[0] = bf2f(h[(size_t)node * D + lane]) * di;
    }
    const int beg = rowptr[node];
    const int end = rowptr[node + 1];
    for (int e = beg; e < end; e += 8) {
        int ss[8]; float nn[8];
        #pragma unroll
        for (int u = 0; u < 8; ++u) {
            int idx = e + u;
            int cl = idx < end ? idx : (end - 1);
            ss[u] = colIdx[cl];                       // wave-uniform scalar load
            nn[u] = idx < end ? valNorm[cl] : 0.0f;
        }
        if constexpr (PER == 2) {
            unsigned hv[8];
            #pragma unroll
            for (int u = 0; u < 8; ++u)
                hv[u] = *(const unsigned*)&h[(size_t)ss[u] * D + lane * 2];
            #pragma unroll
            for (int u = 0; u < 8; ++u) {
                acc[0] += bf2f((unsigned short)hv[u]) * nn[u];
                acc[1] += bf2f((unsigned short)(hv[u] >> 16)) * nn[u];
            }
        } else {
            unsigned short hv[8];
            #pragma unroll
            for (int u = 0; u < 8; ++u) hv[u] = h[(size_t)ss[u] * D + lane];
            #pragma unroll
            for (int u = 0; u < 8; ++u) acc[0] += bf2f(hv[u]) * nn[u];
        }
    }
    if constexpr (PER == 2) {
        float v0 = acc[0] * di + bias[lane * 2];
        float v1 = acc[1] * di + bias[lane * 2 + 1];
        if constexpr (ACT == 1) { v0 = tanhf(v0); v1 = tanhf(v1); }
        else                    { v0 = sigmoidf_(v0); v1 = sigmoidf_(v1); }
        unsigned pk = (unsigned)f2bf(v0) | ((unsigned)f2bf(v1) << 16);
        *(unsigned*)&out[(size_t)node * ldo + lane * 2] = pk;
    } else {
        float v = acc[0] * di + bias[lane];
        v = (ACT == 1) ? tanhf(v) : sigmoidf_(v);
        out[(size_t)node * ldo + lane] = f2bf(v);
    }
}

// ---------------------------------------------------------------- W prep
template<int M>
__global__ __launch_bounds__(TPB) void k_prep_w(const float* __restrict__ W,
                                                unsigned short* __restrict__ Wt) {
    int c = blockIdx.x * TPB + threadIdx.x;
    if (c >= M * 16) return;
    int m = c >> 4, k0 = (c & 15) << 3;
    unsigned o[4];
    #pragma unroll
    for (int j = 0; j < 4; ++j) {
        unsigned lo = f2bf(W[(size_t)(k0 + 2 * j) * M + m]);
        unsigned hi = f2bf(W[(size_t)(k0 + 2 * j + 1) * M + m]);
        o[j] = lo | (hi << 16);
    }
    unsigned byte = ((unsigned)c * 16) ^ (unsigned)((m & 7) << 4);
    *(uint4*)((char*)Wt + byte) = *(uint4*)o;
}

// ---------------------------------------------------------------- MFMA GEMM
template<int M, int ACT, bool A_BF16, bool OUT_F32>
__global__ __launch_bounds__(TPB) void k_mgemm(const void* __restrict__ Ap,
                                               const unsigned short* __restrict__ Wtg,
                                               const float* __restrict__ bias,
                                               void* __restrict__ Cp, int ldc,
                                               int coff, int n) {
    constexpr int K = 128;
    __shared__ __align__(16) unsigned short Al[128 * K];
    __shared__ __align__(16) unsigned short Wt[M * K];

    const int tid = threadIdx.x;
    const int wv = tid >> 6;
    const int ln = tid & 63;
    const int rbase = blockIdx.x * 128;

    constexpr int WCH = (M * K * 2) / 1024;
    #pragma unroll
    for (int c = 0; c < WCH / 4; ++c) {
        int cc = wv * (WCH / 4) + c;
        gld_lds16((const char*)Wtg + cc * 1024 + ln * 16, (char*)Wt + cc * 1024);
    }

    if (A_BF16 && rbase + 128 <= n) {
        #pragma unroll
        for (int it = 0; it < 8; ++it) {
            unsigned dbase = (unsigned)(wv * 8 + it) * 1024;
            unsigned d = dbase + (unsigned)ln * 16;
            unsigned row = d >> 8;
            unsigned s = d ^ ((row & 7) << 4);
            gld_lds16((const char*)Ap + (size_t)rbase * 256 + s, (char*)Al + dbase);
        }
    } else {
        for (int ch = tid; ch < 128 * 16; ch += TPB) {
            int row = ch >> 4;
            int col8 = (ch & 15) * 8;
            int r = rbase + row;
            unsigned o4[4] = {0u, 0u, 0u, 0u};
            if (r < n) {
                if constexpr (A_BF16) {
                    uint4 v = *(const uint4*)((const unsigned short*)Ap + (size_t)r * 128 + col8);
                    o4[0] = v.x; o4[1] = v.y; o4[2] = v.z; o4[3] = v.w;
                } else {
                    float4 a = *(const float4*)((const float*)Ap + (size_t)r * 128 + col8);
                    float4 b = *(const float4*)((const float*)Ap + (size_t)r * 128 + col8 + 4);
                    o4[0] = (unsigned)f2bf(a.x) | ((unsigned)f2bf(a.y) << 16);
                    o4[1] = (unsigned)f2bf(a.z) | ((unsigned)f2bf(a.w) << 16);
                    o4[2] = (unsigned)f2bf(b.x) | ((unsigned)f2bf(b.y) << 16);
                    o4[3] = (unsigned)f2bf(b.z) | ((unsigned)f2bf(b.w) << 16);
                }
            }
            unsigned byte = ((unsigned)ch * 16) ^ (unsigned)((row & 7) << 4);
            *(uint4*)((char*)Al + byte) = *(uint4*)o4;
        }
    }
    __syncthreads();

    const int lr = ln & 15;
    const int lg = ln >> 4;

    constexpr int MF = M / 16;
    f32x4 acc[2][MF];
    #pragma unroll
    for (int i = 0; i < 2; ++i)
        #pragma unroll
        for (int j = 0; j < MF; ++j) acc[i][j] = (f32x4){0.f, 0.f, 0.f, 0.f};

    #pragma unroll
    for (int kk = 0; kk < 4; ++kk) {
        const int kb = kk * 64 + lg * 16;
        bf16x8 af[2];
        #pragma unroll
        for (int rf = 0; rf < 2; ++rf) {
            int row = wv * 32 + rf * 16 + lr;
            unsigned byte = (unsigned)(row * 256 + kb) ^ (unsigned)((row & 7) << 4);
            af[rf] = *(bf16x8*)((char*)Al + byte);
        }
        #pragma unroll
        for (int mf = 0; mf < MF; ++mf) {
            int col = mf * 16 + lr;
            unsigned byte = (unsigned)(col * 256 + kb) ^ (unsigned)((col & 7) << 4);
            bf16x8 bfg = *(bf16x8*)((char*)Wt + byte);
            acc[0][mf] = __builtin_amdgcn_mfma_f32_16x16x32_bf16(af[0], bfg, acc[0][mf], 0, 0, 0);
            acc[1][mf] = __builtin_amdgcn_mfma_f32_16x16x32_bf16(af[1], bfg, acc[1][mf], 0, 0, 0);
        }
    }

    #pragma unroll
    for (int rf = 0; rf < 2; ++rf) {
        #pragma unroll
        for (int j = 0; j < 4; ++j) {
            int row = rbase + wv * 32 + rf * 16 + lg * 4 + j;
            if (row < n) {
                #pragma unroll
                for (int mf = 0; mf < MF; ++mf) {
                    int col = mf * 16 + lr;
                    float v = acc[rf][mf][j] + (bias ? bias[col] : 0.0f);
                    if constexpr (ACT == 1) v = tanhf(v);
                    else if constexpr (ACT == 2) v = sigmoidf_(v);
                    if constexpr (OUT_F32)
                        ((float*)Cp)[(size_t)row * ldc + coff + col] = v;
                    else
                        ((unsigned short*)Cp)[(size_t)row * ldc + coff + col] = f2bf(v);
                }
            }
        }
    }
}

// ---------------------------------------------------------------- small SIMT GEMM (gdv)
template<int K, int M, int RI>
__global__ __launch_bounds__(TPB) void k_gemm_s(const float* __restrict__ A, int lda,
                                                const float* __restrict__ W,
                                                const float* __restrict__ bias,
                                                unsigned short* __restrict__ C, int ldc,
                                                int coff, int n) {
    constexpr int TPR = M;
    constexpr int G = TPB / TPR;
    constexpr int RT = G * RI;
    __shared__ float Alds[RT * K];
    __shared__ float Wlds[K * M];
    for (int i = threadIdx.x; i < K * M; i += TPB) Wlds[i] = W[i];

    const int c0 = threadIdx.x % TPR;
    const int rg = threadIdx.x / TPR;
    const int rbase = blockIdx.x * RT;

    for (int i = threadIdx.x; i < RT * K; i += TPB) {
        int rr = i / K;
        int r = rbase + rr;
        Alds[i] = (r < n) ? A[(size_t)r * lda + (i - rr * K)] : 0.0f;
    }
    __syncthreads();

    float acc[RI];
    #pragma unroll
    for (int j = 0; j < RI; ++j) acc[j] = 0.0f;
    const float* Ab = &Alds[rg * RI * K];
    #pragma unroll 4
    for (int k = 0; k < K; ++k) {
        float wv = Wlds[k * M + c0];
        #pragma unroll
        for (int j = 0; j < RI; ++j) acc[j] += Ab[j * K + k] * wv;
    }
    #pragma unroll
    for (int j = 0; j < RI; ++j) {
        int r = rbase + rg * RI + j;
        if (r < n) C[(size_t)r * ldc + coff + c0] = f2bf(sigmoidf_(acc[j] + bias[c0]));
    }
}

__global__ __launch_bounds__(TPB) void k_pr(const float* __restrict__ pr,
                                            const float* __restrict__ prW,
                                            const float* __restrict__ prB,
                                            unsigned short* __restrict__ enc, int n) {
    int i = blockIdx.x * TPB + threadIdx.x;
    if (i < n * 32) {
        int node = i >> 5;
        int c = i & 31;
        float v = pr[node] * prW[c] + prB[c];
        enc[(size_t)node * 128 + 96 + c] = f2bf(sigmoidf_(v));
    }
}

// ---------------------------------------------------------------- launch

extern "C" void kernel_launch(void* const* d_in, const int* in_sizes, int n_in,
                              void* d_out, int out_size, void* d_ws, size_t ws_size,
                              hipStream_t stream) {
    const float* feat = (const float*)d_in[0];
    const float* gdv  = (const float*)d_in[1];
    const float* pr   = (const float*)d_in[2];
    const int*   eidx = (const int*)d_in[3];
    const float* ew   = (const float*)d_in[4];
    const float* W1   = (const float*)d_in[5];
    const float* b1   = (const float*)d_in[6];
    const float* W2   = (const float*)d_in[7];
    const float* b2   = (const float*)d_in[8];
    const float* gdvW = (const float*)d_in[9];
    const float* gdvB = (const float*)d_in[10];
    const float* prW  = (const float*)d_in[11];
    const float* prB  = (const float*)d_in[12];
    const float* eW1  = (const float*)d_in[13];
    const float* eB1  = (const float*)d_in[14];
    const float* eW2  = (const float*)d_in[15];
    const float* eB2  = (const float*)d_in[16];
    float* out = (float*)d_out;

    const int N = in_sizes[0] / 128;
    const int E = in_sizes[4];
    const int* srcA = eidx;
    const int* dstA = eidx + E;

    char* p = (char*)d_ws;
    auto alloc = [&](size_t bytes) {
        char* r = p;
        p += (bytes + 255) & ~(size_t)255;
        return r;
    };
    unsigned* counts  = (unsigned*)alloc((size_t)N * 4);
    unsigned* epos    = (unsigned*)alloc((size_t)E * 4);
    float*    dinv    = (float*)   alloc((size_t)N * 4);
    int*      rowptr  = (int*)     alloc((size_t)(N + 1) * 4);
    int*      bsums   = (int*)     alloc(256 * 4);
    int*      colIdx  = (int*)     alloc((size_t)E * 4);
    float*    valNorm = (float*)   alloc((size_t)E * 4);
    unsigned short* wt1  = (unsigned short*)alloc(128 * 128 * 2);
    unsigned short* wt2  = (unsigned short*)alloc(128 * 64 * 2);
    unsigned short* wtE1 = (unsigned short*)alloc(128 * 128 * 2);
    unsigned short* wtE2 = (unsigned short*)alloc(128 * 128 * 2);
    unsigned short* bufA = (unsigned short*)alloc((size_t)N * 128 * 2);  // h -> h2 -> enc1
    unsigned short* bufB = (unsigned short*)alloc((size_t)N * 128 * 2);  // h1 -> enc

    const int nbN = (N + TPB - 1) / TPB;
    const int nbE = (E + TPB - 1) / TPB;
    const int nscan = (N + SCAN_CHUNK - 1) / SCAN_CHUNK;
    const int nbM = (N + 127) / 128;

    // weight prep (independent of CSR)
    k_prep_w<128><<<8, TPB, 0, stream>>>(W1, wt1);
    k_prep_w<64><<<4, TPB, 0, stream>>>(W2, wt2);
    k_prep_w<128><<<8, TPB, 0, stream>>>(eW1, wtE1);
    k_prep_w<128><<<8, TPB, 0, stream>>>(eW2, wtE2);

    // CSR build: 1 returning atomic/edge; deg from CSR sum; src-factor scale
    k_zero<<<nbN, TPB, 0, stream>>>(counts, N);
    k_pass1<<<nbE, TPB, 0, stream>>>(dstA, counts, epos, E);
    k_scan_a<<<nscan, TPB, 0, stream>>>(counts, rowptr, bsums, N);
    k_scan_b<<<1, 128, 0, stream>>>(bsums, nscan);
    k_scan_c<<<nbN, TPB, 0, stream>>>(rowptr, bsums, N, E);
    k_fill<<<nbE, TPB, 0, stream>>>(srcA, dstA, ew, rowptr, epos, colIdx, valNorm, E);
    k_deg<<<nbN, TPB, 0, stream>>>(rowptr, valNorm, dinv, N);
    k_scale<<<nbE, TPB, 0, stream>>>(colIdx, dinv, valNorm, E);

    // h = feat @ W1                       (bufA bf16, ld128)
    k_mgemm<128, 0, false, false><<<nbM, TPB, 0, stream>>>(
        feat, wt1, nullptr, bufA, 128, 0, N);
    // h1 = tanh(agg(h) + b1)              (bufB bf16, ld128)
    k_agg<128, 1><<<(N + 3) / 4, TPB, 0, stream>>>(
        bufA, rowptr, colIdx, valNorm, dinv, b1, bufB, 128, N);
    // h2 = h1 @ W2                        (bufA bf16, ld64)
    k_mgemm<64, 0, true, false><<<nbM, TPB, 0, stream>>>(
        bufB, wt2, nullptr, bufA, 64, 0, N);
    // enc[:,0:64] = sigmoid(agg(h2) + b2) (bufB bf16, ld128)
    k_agg<64, 2><<<(N + 3) / 4, TPB, 0, stream>>>(
        bufA, rowptr, colIdx, valNorm, dinv, b2, bufB, 128, N);
    // enc[:,64:96] = sigmoid(gdv @ gdvW + gdvB)
    k_gemm_s<73, 32, 4><<<(N + 31) / 32, TPB, 0, stream>>>(
        gdv, 73, gdvW, gdvB, bufB, 128, 64, N);
    // enc[:,96:128] = sigmoid(pr * prW + prB)
    k_pr<<<((size_t)N * 32 + TPB - 1) / TPB, TPB, 0, stream>>>(pr, prW, prB, bufB, N);
    // enc1 = tanh(enc @ eW1 + eB1)        (bufA bf16, ld128)
    k_mgemm<128, 1, true, false><<<nbM, TPB, 0, stream>>>(
        bufB, wtE1, eB1, bufA, 128, 0, N);
    // out = enc1 @ eW2 + eB2              (d_out f32)
    k_mgemm<128, 0, true, true><<<nbM, TPB, 0, stream>>>(
        bufA, wtE2, eB2, out, 128, 0, N);
}

// Round 7
// 539.567 us; speedup vs baseline: 2.1680x; 1.1115x over previous
//
#include <hip/hip_runtime.h>
#include <hip/hip_bf16.h>
#include <cstdint>
#include <cstddef>

#define TPB 256
#define SCAN_CHUNK 1024

typedef short bf16x8 __attribute__((ext_vector_type(8)));
typedef float f32x4 __attribute__((ext_vector_type(4)));

__device__ __forceinline__ float sigmoidf_(float x) {
    return 1.0f / (1.0f + __expf(-x));
}
__device__ __forceinline__ unsigned short f2bf(float x) {   // RNE
    unsigned u = __float_as_uint(x);
    u += 0x7FFF + ((u >> 16) & 1);
    return (unsigned short)(u >> 16);
}
__device__ __forceinline__ float bf2f(unsigned short b) {
    return __uint_as_float(((unsigned)b) << 16);
}

// async 16B global->LDS: global src is PER-LANE, LDS dest is wave-uniform base
__device__ __forceinline__ void gld_lds16(const void* gsrc, void* ldst) {
    __builtin_amdgcn_global_load_lds(
        (const __attribute__((address_space(1))) unsigned*)gsrc,
        (__attribute__((address_space(3))) unsigned*)ldst, 16, 0, 0);
}

// ---------------------------------------------------------------- W prep body
template<int M>
__device__ __forceinline__ void prep_w_body(const float* __restrict__ W,
                                            unsigned short* __restrict__ Wt, int c) {
    if (c >= M * 16) return;
    int m = c >> 4, k0 = (c & 15) << 3;
    unsigned o[4];
    #pragma unroll
    for (int j = 0; j < 4; ++j) {
        unsigned lo = f2bf(W[(size_t)(k0 + 2 * j) * M + m]);
        unsigned hi = f2bf(W[(size_t)(k0 + 2 * j + 1) * M + m]);
        o[j] = lo | (hi << 16);
    }
    unsigned byte = ((unsigned)c * 16) ^ (unsigned)((m & 7) << 4);
    *(uint4*)((char*)Wt + byte) = *(uint4*)o;
}

// prep fat kernel: zero counts + convert/swizzle all 4 weights
__global__ __launch_bounds__(TPB) void k_prep(const float* W1, unsigned short* wt1,
                                              const float* W2, unsigned short* wt2,
                                              const float* E1, unsigned short* wtE1,
                                              const float* E2, unsigned short* wtE2,
                                              unsigned* counts, int n, int nbZ) {
    int bid = blockIdx.x;
    if (bid < nbZ) {
        int i = bid * TPB + threadIdx.x;
        if (i < n) counts[i] = 0u;
    } else {
        int t = bid - nbZ;
        if (t < 8)       prep_w_body<128>(W1, wt1, t * TPB + threadIdx.x);
        else if (t < 12) prep_w_body<64>(W2, wt2, (t - 8) * TPB + threadIdx.x);
        else if (t < 20) prep_w_body<128>(E1, wtE1, (t - 12) * TPB + threadIdx.x);
        else             prep_w_body<128>(E2, wtE2, (t - 20) * TPB + threadIdx.x);
    }
}

// ---------------------------------------------------------------- MFMA GEMM body
// C(n x M) = act(A(n x 128) @ W + bias). K=128 one LDS pass. 4 waves x 32 rows.
template<int M, int ACT, bool A_BF16, bool OUT_F32>
__device__ __forceinline__ void mgemm_body(const void* __restrict__ Ap,
                                           const unsigned short* __restrict__ Wtg,
                                           const float* __restrict__ bias,
                                           void* __restrict__ Cp, int ldc, int coff,
                                           int n, int tile,
                                           unsigned short* Al, unsigned short* Wt) {
    const int tid = threadIdx.x;
    const int wv = tid >> 6;
    const int ln = tid & 63;
    const int rbase = tile * 128;

    constexpr int WCH = (M * 128 * 2) / 1024;
    #pragma unroll
    for (int c = 0; c < WCH / 4; ++c) {
        int cc = wv * (WCH / 4) + c;
        gld_lds16((const char*)Wtg + cc * 1024 + ln * 16, (char*)Wt + cc * 1024);
    }

    if (A_BF16 && rbase + 128 <= n) {
        #pragma unroll
        for (int it = 0; it < 8; ++it) {
            unsigned dbase = (unsigned)(wv * 8 + it) * 1024;
            unsigned d = dbase + (unsigned)ln * 16;
            unsigned row = d >> 8;
            unsigned s = d ^ ((row & 7) << 4);
            gld_lds16((const char*)Ap + (size_t)rbase * 256 + s, (char*)Al + dbase);
        }
    } else {
        for (int ch = tid; ch < 128 * 16; ch += TPB) {
            int row = ch >> 4;
            int col8 = (ch & 15) * 8;
            int r = rbase + row;
            unsigned o4[4] = {0u, 0u, 0u, 0u};
            if (r < n) {
                if constexpr (A_BF16) {
                    uint4 v = *(const uint4*)((const unsigned short*)Ap + (size_t)r * 128 + col8);
                    o4[0] = v.x; o4[1] = v.y; o4[2] = v.z; o4[3] = v.w;
                } else {
                    float4 a = *(const float4*)((const float*)Ap + (size_t)r * 128 + col8);
                    float4 b = *(const float4*)((const float*)Ap + (size_t)r * 128 + col8 + 4);
                    o4[0] = (unsigned)f2bf(a.x) | ((unsigned)f2bf(a.y) << 16);
                    o4[1] = (unsigned)f2bf(a.z) | ((unsigned)f2bf(a.w) << 16);
                    o4[2] = (unsigned)f2bf(b.x) | ((unsigned)f2bf(b.y) << 16);
                    o4[3] = (unsigned)f2bf(b.z) | ((unsigned)f2bf(b.w) << 16);
                }
            }
            unsigned byte = ((unsigned)ch * 16) ^ (unsigned)((row & 7) << 4);
            *(uint4*)((char*)Al + byte) = *(uint4*)o4;
        }
    }
    __syncthreads();

    const int lr = ln & 15;
    const int lg = ln >> 4;

    constexpr int MF = M / 16;
    f32x4 acc[2][MF];
    #pragma unroll
    for (int i = 0; i < 2; ++i)
        #pragma unroll
        for (int j = 0; j < MF; ++j) acc[i][j] = (f32x4){0.f, 0.f, 0.f, 0.f};

    #pragma unroll
    for (int kk = 0; kk < 4; ++kk) {
        const int kb = kk * 64 + lg * 16;
        bf16x8 af[2];
        #pragma unroll
        for (int rf = 0; rf < 2; ++rf) {
            int row = wv * 32 + rf * 16 + lr;
            unsigned byte = (unsigned)(row * 256 + kb) ^ (unsigned)((row & 7) << 4);
            af[rf] = *(bf16x8*)((char*)Al + byte);
        }
        #pragma unroll
        for (int mf = 0; mf < MF; ++mf) {
            int col = mf * 16 + lr;
            unsigned byte = (unsigned)(col * 256 + kb) ^ (unsigned)((col & 7) << 4);
            bf16x8 bfg = *(bf16x8*)((char*)Wt + byte);
            acc[0][mf] = __builtin_amdgcn_mfma_f32_16x16x32_bf16(af[0], bfg, acc[0][mf], 0, 0, 0);
            acc[1][mf] = __builtin_amdgcn_mfma_f32_16x16x32_bf16(af[1], bfg, acc[1][mf], 0, 0, 0);
        }
    }

    #pragma unroll
    for (int rf = 0; rf < 2; ++rf) {
        #pragma unroll
        for (int j = 0; j < 4; ++j) {
            int row = rbase + wv * 32 + rf * 16 + lg * 4 + j;
            if (row < n) {
                #pragma unroll
                for (int mf = 0; mf < MF; ++mf) {
                    int col = mf * 16 + lr;
                    float v = acc[rf][mf][j] + (bias ? bias[col] : 0.0f);
                    if constexpr (ACT == 1) v = tanhf(v);
                    else if constexpr (ACT == 2) v = sigmoidf_(v);
                    if constexpr (OUT_F32)
                        ((float*)Cp)[(size_t)row * ldc + coff + col] = v;
                    else
                        ((unsigned short*)Cp)[(size_t)row * ldc + coff + col] = f2bf(v);
                }
            }
        }
    }
}

// fat: GEMM1 (feat@W1, f32 A) ∥ pass1 histogram (independent work)
__global__ __launch_bounds__(TPB) void k_g1p1(const float* __restrict__ feat,
                                              const unsigned short* __restrict__ wt1,
                                              unsigned short* __restrict__ bufA,
                                              int n, int nbM,
                                              const int* __restrict__ dst,
                                              unsigned* __restrict__ counts,
                                              unsigned* __restrict__ epos, int E) {
    __shared__ __align__(16) unsigned short Al[128 * 128];
    __shared__ __align__(16) unsigned short Wt[128 * 128];
    if (blockIdx.x < nbM) {
        mgemm_body<128, 0, false, false>(feat, wt1, nullptr, bufA, 128, 0, n,
                                         blockIdx.x, Al, Wt);
    } else {
        int e = (blockIdx.x - nbM) * TPB + threadIdx.x;
        if (e < E) epos[e] = atomicAdd(&counts[dst[e]], 1u);
    }
}

// standalone GEMM (h1@W2, M=64)
__global__ __launch_bounds__(TPB) void k_mgemm64(const unsigned short* __restrict__ Ap,
                                                 const unsigned short* __restrict__ Wtg,
                                                 unsigned short* __restrict__ Cp, int n) {
    __shared__ __align__(16) unsigned short Al[128 * 128];
    __shared__ __align__(16) unsigned short Wt[64 * 128];
    mgemm_body<64, 0, true, false>(Ap, Wtg, nullptr, Cp, 64, 0, n, blockIdx.x, Al, Wt);
}

// fused encoder: out = tanh(enc@eW1+b1) @ eW2 + b2  (intermediate in LDS)
__global__ __launch_bounds__(TPB) void k_enc2(const unsigned short* __restrict__ enc,
                                              const unsigned short* __restrict__ w1g,
                                              const float* __restrict__ b1,
                                              const unsigned short* __restrict__ w2g,
                                              const float* __restrict__ b2,
                                              float* __restrict__ out, int n) {
    __shared__ __align__(16) unsigned short Al[128 * 128];
    __shared__ __align__(16) unsigned short Wt[128 * 128];
    const int tid = threadIdx.x;
    const int wv = tid >> 6;
    const int ln = tid & 63;
    const int rbase = blockIdx.x * 128;
    const int lr = ln & 15;
    const int lg = ln >> 4;

    // stage W1 + A tile
    #pragma unroll
    for (int c = 0; c < 8; ++c) {
        int cc = wv * 8 + c;
        gld_lds16((const char*)w1g + cc * 1024 + ln * 16, (char*)Wt + cc * 1024);
    }
    if (rbase + 128 <= n) {
        #pragma unroll
        for (int it = 0; it < 8; ++it) {
            unsigned dbase = (unsigned)(wv * 8 + it) * 1024;
            unsigned d = dbase + (unsigned)ln * 16;
            unsigned row = d >> 8;
            unsigned s = d ^ ((row & 7) << 4);
            gld_lds16((const char*)enc + (size_t)rbase * 256 + s, (char*)Al + dbase);
        }
    } else {
        for (int ch = tid; ch < 128 * 16; ch += TPB) {
            int row = ch >> 4;
            int col8 = (ch & 15) * 8;
            int r = rbase + row;
            unsigned o4[4] = {0u, 0u, 0u, 0u};
            if (r < n) {
                uint4 v = *(const uint4*)(enc + (size_t)r * 128 + col8);
                o4[0] = v.x; o4[1] = v.y; o4[2] = v.z; o4[3] = v.w;
            }
            unsigned byte = ((unsigned)ch * 16) ^ (unsigned)((row & 7) << 4);
            *(uint4*)((char*)Al + byte) = *(uint4*)o4;
        }
    }
    __syncthreads();

    f32x4 acc[2][8];
    #pragma unroll
    for (int i = 0; i < 2; ++i)
        #pragma unroll
        for (int j = 0; j < 8; ++j) acc[i][j] = (f32x4){0.f, 0.f, 0.f, 0.f};

    #pragma unroll
    for (int kk = 0; kk < 4; ++kk) {
        const int kb = kk * 64 + lg * 16;
        bf16x8 af[2];
        #pragma unroll
        for (int rf = 0; rf < 2; ++rf) {
            int row = wv * 32 + rf * 16 + lr;
            unsigned byte = (unsigned)(row * 256 + kb) ^ (unsigned)((row & 7) << 4);
            af[rf] = *(bf16x8*)((char*)Al + byte);
        }
        #pragma unroll
        for (int mf = 0; mf < 8; ++mf) {
            int col = mf * 16 + lr;
            unsigned byte = (unsigned)(col * 256 + kb) ^ (unsigned)((col & 7) << 4);
            bf16x8 bfg = *(bf16x8*)((char*)Wt + byte);
            acc[0][mf] = __builtin_amdgcn_mfma_f32_16x16x32_bf16(af[0], bfg, acc[0][mf], 0, 0, 0);
            acc[1][mf] = __builtin_amdgcn_mfma_f32_16x16x32_bf16(af[1], bfg, acc[1][mf], 0, 0, 0);
        }
    }
    __syncthreads();   // all waves done reading Wt (and Al)

    // stage W2 early (hides under tanh+writes)...
    #pragma unroll
    for (int c = 0; c < 8; ++c) {
        int cc = wv * 8 + c;
        gld_lds16((const char*)w2g + cc * 1024 + ln * 16, (char*)Wt + cc * 1024);
    }
    // ...write tanh(acc+b1) back into Al (each wave owns its 32 rows)
    #pragma unroll
    for (int rf = 0; rf < 2; ++rf) {
        #pragma unroll
        for (int j = 0; j < 4; ++j) {
            int rl = wv * 32 + rf * 16 + lg * 4 + j;
            #pragma unroll
            for (int mf = 0; mf < 8; ++mf) {
                int col = mf * 16 + lr;
                float v = tanhf(acc[rf][mf][j] + b1[col]);
                unsigned byte = (unsigned)(rl * 256 + col * 2) ^ (unsigned)((rl & 7) << 4);
                *(unsigned short*)((char*)Al + byte) = f2bf(v);
            }
        }
    }
    __syncthreads();   // drains W2 loads + Al writes

    #pragma unroll
    for (int i = 0; i < 2; ++i)
        #pragma unroll
        for (int j = 0; j < 8; ++j) acc[i][j] = (f32x4){0.f, 0.f, 0.f, 0.f};

    #pragma unroll
    for (int kk = 0; kk < 4; ++kk) {
        const int kb = kk * 64 + lg * 16;
        bf16x8 af[2];
        #pragma unroll
        for (int rf = 0; rf < 2; ++rf) {
            int row = wv * 32 + rf * 16 + lr;
            unsigned byte = (unsigned)(row * 256 + kb) ^ (unsigned)((row & 7) << 4);
            af[rf] = *(bf16x8*)((char*)Al + byte);
        }
        #pragma unroll
        for (int mf = 0; mf < 8; ++mf) {
            int col = mf * 16 + lr;
            unsigned byte = (unsigned)(col * 256 + kb) ^ (unsigned)((col & 7) << 4);
            bf16x8 bfg = *(bf16x8*)((char*)Wt + byte);
            acc[0][mf] = __builtin_amdgcn_mfma_f32_16x16x32_bf16(af[0], bfg, acc[0][mf], 0, 0, 0);
            acc[1][mf] = __builtin_amdgcn_mfma_f32_16x16x32_bf16(af[1], bfg, acc[1][mf], 0, 0, 0);
        }
    }

    #pragma unroll
    for (int rf = 0; rf < 2; ++rf) {
        #pragma unroll
        for (int j = 0; j < 4; ++j) {
            int row = rbase + wv * 32 + rf * 16 + lg * 4 + j;
            if (row < n) {
                #pragma unroll
                for (int mf = 0; mf < 8; ++mf) {
                    int col = mf * 16 + lr;
                    out[(size_t)row * 128 + col] = acc[rf][mf][j] + b2[col];
                }
            }
        }
    }
}

// ---------------------------------------------------------------- scan chain

__global__ __launch_bounds__(TPB) void k_scan_a(const unsigned* __restrict__ counts,
                                                int* __restrict__ rowptr,
                                                int* __restrict__ bsums, int n) {
    __shared__ int s[SCAN_CHUNK];
    int base = blockIdx.x * SCAN_CHUNK;
    int orig[4];
    #pragma unroll
    for (int j0 = 0; j0 < 4; ++j0) {
        int j = threadIdx.x + j0 * TPB;
        int v = (base + j < n) ? (int)counts[base + j] : 0;
        orig[j0] = v;
        s[j] = v;
    }
    __syncthreads();
    for (int off = 1; off < SCAN_CHUNK; off <<= 1) {
        int t[4];
        #pragma unroll
        for (int j0 = 0; j0 < 4; ++j0) {
            int j = threadIdx.x + j0 * TPB;
            t[j0] = (j >= off) ? s[j - off] : 0;
        }
        __syncthreads();
        #pragma unroll
        for (int j0 = 0; j0 < 4; ++j0) {
            int j = threadIdx.x + j0 * TPB;
            s[j] += t[j0];
        }
        __syncthreads();
    }
    #pragma unroll
    for (int j0 = 0; j0 < 4; ++j0) {
        int j = threadIdx.x + j0 * TPB;
        if (base + j < n) rowptr[base + j] = s[j] - orig[j0];
    }
    if (threadIdx.x == 0) bsums[blockIdx.x] = s[SCAN_CHUNK - 1];
}

__global__ void k_scan_b(int* bsums, int nb) {   // <<<1,128>>>
    __shared__ int s[128];
    int t = threadIdx.x;
    int v = (t < nb) ? bsums[t] : 0;
    s[t] = v;
    __syncthreads();
    for (int off = 1; off < 128; off <<= 1) {
        int x = (t >= off) ? s[t - off] : 0;
        __syncthreads();
        s[t] += x;
        __syncthreads();
    }
    if (t < nb) bsums[t] = s[t] - v;
}

__global__ __launch_bounds__(TPB) void k_scan_c(int* __restrict__ rowptr,
                                                const int* __restrict__ bsums,
                                                int n, int E) {
    int i = blockIdx.x * TPB + threadIdx.x;
    if (i < n) rowptr[i] += bsums[i / SCAN_CHUNK];
    if (i == 0) rowptr[n] = E;
}

// atomic-free fill: ONE packed 8B scatter per edge {src, raw ew}
__global__ __launch_bounds__(TPB) void k_fill(const int* __restrict__ src,
                                              const int* __restrict__ dst,
                                              const float* __restrict__ ew,
                                              const int* __restrict__ rowptr,
                                              const unsigned* __restrict__ epos,
                                              uint2* __restrict__ edges, int E) {
    int e = blockIdx.x * TPB + threadIdx.x;
    if (e < E) {
        unsigned slot = (unsigned)rowptr[dst[e]] + epos[e];
        uint2 pk;
        pk.x = (unsigned)src[e];
        pk.y = __float_as_uint(ew[e]);
        edges[slot] = pk;
    }
}

// deg = 1 + row sum of raw weights; dinv = rsqrt
__global__ __launch_bounds__(TPB) void k_deg(const int* __restrict__ rowptr,
                                             const uint2* __restrict__ edges,
                                             float* __restrict__ dinv, int n) {
    int i = blockIdx.x * TPB + threadIdx.x;
    if (i >= n) return;
    int beg = rowptr[i], end = rowptr[i + 1];
    float s = 1.0f;
    for (int e = beg; e < end; ++e) s += __uint_as_float(edges[e].y);
    dinv[i] = rsqrtf(s);
}

// ---------------------------------------------------------------- aggregation
// one wave per node. out = dinv_d*(dinv_d*h_d + sum (ew*dinv_s)*h_s) + bias
template<int D, int ACT>
__device__ __forceinline__ void agg_body(const unsigned short* __restrict__ h,
                                         const int* __restrict__ rowptr,
                                         const uint2* __restrict__ edges,
                                         const float* __restrict__ dinv,
                                         const float* __restrict__ bias,
                                         unsigned short* __restrict__ out,
                                         int ldo, int n, int node) {
    const int lane = threadIdx.x & 63;
    constexpr int PER = D / 64;
    float acc[PER];
    const float di = dinv[node];
    if constexpr (PER == 2) {
        unsigned hv = *(const unsigned*)&h[(size_t)node * D + lane * 2];
        acc[0] = bf2f((unsigned short)hv) * di;
        acc[1] = bf2f((unsigned short)(hv >> 16)) * di;
    } else {
        acc[0] = bf2f(h[(size_t)node * D + lane]) * di;
    }
    const int beg = rowptr[node];
    const int end = rowptr[node + 1];
    for (int e = beg; e < end; e += 8) {
        int ss[8]; float ww[8];
        #pragma unroll
        for (int u = 0; u < 8; ++u) {
            int idx = e + u;
            int cl = idx < end ? idx : (end - 1);
            uint2 ed = edges[cl];                    // wave-uniform 8B load
            ss[u] = (int)ed.x;
            ww[u] = idx < end ? __uint_as_float(ed.y) : 0.0f;
        }
        float nn[8];
        #pragma unroll
        for (int u = 0; u < 8; ++u) nn[u] = ww[u] * dinv[ss[u]];
        if constexpr (PER == 2) {
            unsigned hv[8];
            #pragma unroll
            for (int u = 0; u < 8; ++u)
                hv[u] = *(const unsigned*)&h[(size_t)ss[u] * D + lane * 2];
            #pragma unroll
            for (int u = 0; u < 8; ++u) {
                acc[0] += bf2f((unsigned short)hv[u]) * nn[u];
                acc[1] += bf2f((unsigned short)(hv[u] >> 16)) * nn[u];
            }
        } else {
            unsigned short hv[8];
            #pragma unroll
            for (int u = 0; u < 8; ++u) hv[u] = h[(size_t)ss[u] * D + lane];
            #pragma unroll
            for (int u = 0; u < 8; ++u) acc[0] += bf2f(hv[u]) * nn[u];
        }
    }
    if constexpr (PER == 2) {
        float v0 = acc[0] * di + bias[lane * 2];
        float v1 = acc[1] * di + bias[lane * 2 + 1];
        if constexpr (ACT == 1) { v0 = tanhf(v0); v1 = tanhf(v1); }
        else                    { v0 = sigmoidf_(v0); v1 = sigmoidf_(v1); }
        unsigned pk = (unsigned)f2bf(v0) | ((unsigned)f2bf(v1) << 16);
        *(unsigned*)&out[(size_t)node * ldo + lane * 2] = pk;
    } else {
        float v = acc[0] * di + bias[lane];
        v = (ACT == 1) ? tanhf(v) : sigmoidf_(v);
        out[(size_t)node * ldo + lane] = f2bf(v);
    }
}

__global__ __launch_bounds__(TPB) void k_agg128(const unsigned short* __restrict__ h,
                                                const int* __restrict__ rowptr,
                                                const uint2* __restrict__ edges,
                                                const float* __restrict__ dinv,
                                                const float* __restrict__ bias,
                                                unsigned short* __restrict__ out, int n) {
    int node = blockIdx.x * 4 + (threadIdx.x >> 6);
    if (node < n) agg_body<128, 1>(h, rowptr, edges, dinv, bias, out, 128, n, node);
}

// ---------------------------------------------------------------- tail fat kernel
// agg64 (enc[:,0:64]) ∥ gdv GEMM (enc[:,64:96]) ∥ pr (enc[:,96:128])
__device__ __forceinline__ void gemm_s_body(const float* __restrict__ A,
                                            const float* __restrict__ W,
                                            const float* __restrict__ bias,
                                            unsigned short* __restrict__ C,
                                            int n, int tile,
                                            float* Alds, float* Wlds) {
    // K=73, M=32, RI=4, RT=32
    for (int i = threadIdx.x; i < 73 * 32; i += TPB) Wlds[i] = W[i];
    const int c0 = threadIdx.x & 31;
    const int rg = threadIdx.x >> 5;
    const int rbase = tile * 32;
    for (int i = threadIdx.x; i < 32 * 73; i += TPB) {
        int rr = i / 73;
        int r = rbase + rr;
        Alds[i] = (r < n) ? A[(size_t)r * 73 + (i - rr * 73)] : 0.0f;
    }
    __syncthreads();
    float acc[4] = {0.f, 0.f, 0.f, 0.f};
    const float* Ab = &Alds[rg * 4 * 73];
    #pragma unroll 4
    for (int k = 0; k < 73; ++k) {
        float wv = Wlds[k * 32 + c0];
        #pragma unroll
        for (int j = 0; j < 4; ++j) acc[j] += Ab[j * 73 + k] * wv;
    }
    #pragma unroll
    for (int j = 0; j < 4; ++j) {
        int r = rbase + rg * 4 + j;
        if (r < n) C[(size_t)r * 128 + 64 + c0] = f2bf(sigmoidf_(acc[j] + bias[c0]));
    }
}

__global__ __launch_bounds__(TPB) void k_tail(const unsigned short* __restrict__ h2,
                                              const int* __restrict__ rowptr,
                                              const uint2* __restrict__ edges,
                                              const float* __restrict__ dinv,
                                              const float* __restrict__ b2,
                                              unsigned short* __restrict__ enc,
                                              const float* __restrict__ gdv,
                                              const float* __restrict__ gdvW,
                                              const float* __restrict__ gdvB,
                                              const float* __restrict__ pr,
                                              const float* __restrict__ prW,
                                              const float* __restrict__ prB,
                                              int n, int nA, int nG) {
    __shared__ float Alds[32 * 73];
    __shared__ float Wlds[73 * 32];
    int bid = blockIdx.x;
    if (bid < nA) {
        int node = bid * 4 + (threadIdx.x >> 6);
        if (node < n) agg_body<64, 2>(h2, rowptr, edges, dinv, b2, enc, 128, n, node);
    } else if (bid < nA + nG) {
        gemm_s_body(gdv, gdvW, gdvB, enc, n, bid - nA, Alds, Wlds);
    } else {
        int i = (bid - nA - nG) * TPB + threadIdx.x;
        if (i < n * 32) {
            int node = i >> 5;
            int c = i & 31;
            float v = pr[node] * prW[c] + prB[c];
            enc[(size_t)node * 128 + 96 + c] = f2bf(sigmoidf_(v));
        }
    }
}

// ---------------------------------------------------------------- launch

extern "C" void kernel_launch(void* const* d_in, const int* in_sizes, int n_in,
                              void* d_out, int out_size, void* d_ws, size_t ws_size,
                              hipStream_t stream) {
    const float* feat = (const float*)d_in[0];
    const float* gdv  = (const float*)d_in[1];
    const float* pr   = (const float*)d_in[2];
    const int*   eidx = (const int*)d_in[3];
    const float* ew   = (const float*)d_in[4];
    const float* W1   = (const float*)d_in[5];
    const float* b1   = (const float*)d_in[6];
    const float* W2   = (const float*)d_in[7];
    const float* b2   = (const float*)d_in[8];
    const float* gdvW = (const float*)d_in[9];
    const float* gdvB = (const float*)d_in[10];
    const float* prW  = (const float*)d_in[11];
    const float* prB  = (const float*)d_in[12];
    const float* eW1  = (const float*)d_in[13];
    const float* eB1  = (const float*)d_in[14];
    const float* eW2  = (const float*)d_in[15];
    const float* eB2  = (const float*)d_in[16];
    float* out = (float*)d_out;

    const int N = in_sizes[0] / 128;
    const int E = in_sizes[4];
    const int* srcA = eidx;
    const int* dstA = eidx + E;

    char* p = (char*)d_ws;
    auto alloc = [&](size_t bytes) {
        char* r = p;
        p += (bytes + 255) & ~(size_t)255;
        return r;
    };
    unsigned* counts = (unsigned*)alloc((size_t)N * 4);
    unsigned* epos   = (unsigned*)alloc((size_t)E * 4);
    float*    dinv   = (float*)   alloc((size_t)N * 4);
    int*      rowptr = (int*)     alloc((size_t)(N + 1) * 4);
    int*      bsums  = (int*)     alloc(256 * 4);
    uint2*    edges  = (uint2*)   alloc((size_t)E * 8);
    unsigned short* wt1  = (unsigned short*)alloc(128 * 128 * 2);
    unsigned short* wt2  = (unsigned short*)alloc(128 * 64 * 2);
    unsigned short* wtE1 = (unsigned short*)alloc(128 * 128 * 2);
    unsigned short* wtE2 = (unsigned short*)alloc(128 * 128 * 2);
    unsigned short* bufA = (unsigned short*)alloc((size_t)N * 128 * 2);  // h -> h2
    unsigned short* bufB = (unsigned short*)alloc((size_t)N * 128 * 2);  // h1 -> enc

    const int nbN = (N + TPB - 1) / TPB;
    const int nbE = (E + TPB - 1) / TPB;
    const int nscan = (N + SCAN_CHUNK - 1) / SCAN_CHUNK;
    const int nbM = (N + 127) / 128;
    const int nA = (N + 3) / 4;
    const int nG = (N + 31) / 32;
    const int nP = (N * 32 + TPB - 1) / TPB;

    // prep: zero counts + swizzle all weights to bf16
    k_prep<<<nbN + 28, TPB, 0, stream>>>(W1, wt1, W2, wt2, eW1, wtE1, eW2, wtE2,
                                         counts, N, nbN);
    // GEMM1 (feat@W1 -> bufA) ∥ histogram
    k_g1p1<<<nbM + nbE, TPB, 0, stream>>>(feat, wt1, bufA, N, nbM,
                                          dstA, counts, epos, E);
    k_scan_a<<<nscan, TPB, 0, stream>>>(counts, rowptr, bsums, N);
    k_scan_b<<<1, 128, 0, stream>>>(bsums, nscan);
    k_scan_c<<<nbN, TPB, 0, stream>>>(rowptr, bsums, N, E);
    k_fill<<<nbE, TPB, 0, stream>>>(srcA, dstA, ew, rowptr, epos, edges, E);
    k_deg<<<nbN, TPB, 0, stream>>>(rowptr, edges, dinv, N);
    // h1 = tanh(agg(h)+b1) -> bufB
    k_agg128<<<nA, TPB, 0, stream>>>(bufA, rowptr, edges, dinv, b1, bufB, N);
    // h2 = h1 @ W2 -> bufA (ld 64)
    k_mgemm64<<<nbM, TPB, 0, stream>>>(bufB, wt2, bufA, N);
    // enc = [sigmoid(agg(h2)+b2) | sigmoid(gdv@gdvW+gdvB) | sigmoid(pr*prW+prB)]
    k_tail<<<nA + nG + nP, TPB, 0, stream>>>(bufA, rowptr, edges, dinv, b2, bufB,
                                             gdv, gdvW, gdvB, pr, prW, prB, N, nA, nG);
    // out = tanh(enc@eW1+eB1)@eW2 + eB2   (f32)
    k_enc2<<<nbM, TPB, 0, stream>>>(bufB, wtE1, eB1, wtE2, eB2, out, N);
}